// Round 1
// baseline (1206.768 us; speedup 1.0000x reference)
//
#include <hip/hip_runtime.h>
#include <math.h>

// Problem constants (LogitBiasedSelfAttention1D): B=4, C=512, T=2048, H=8, D=64
#define BB 4
#define CC 512
#define TT 2048
#define HH 8
#define DD 64
#define SCALE 0.125f
#define EPS 1e-5f

// Workspace layout (floats):
//   qkvbuf : B*3*C*T = 12,582,912   (layout (b, which, h, t, d))
//   attn   : B*T*C   =  4,194,304
//   biasb  : B*T     =      8,192
//   mu     : B*T
//   rstd   : B*T
// total ~64.1 MiB. hbuf reuses qkvbuf region after attention completes.

// ---------------------------------------------------------------- conv bias
__global__ void conv_bias_k(const float* __restrict__ sqi,
                            const float* __restrict__ wc,
                            const float* __restrict__ bc,
                            float* __restrict__ biasb) {
    int idx = blockIdx.x * 256 + threadIdx.x;
    if (idx >= BB * TT) return;
    int t = idx & (TT - 1);
    float l = (t > 0)      ? sqi[idx - 1] : 0.f;
    float m = sqi[idx];
    float r = (t < TT - 1) ? sqi[idx + 1] : 0.f;
    biasb[idx] = wc[0] * l + wc[1] * m + wc[2] * r + bc[0];
}

// ---------------------------------------------------------------- QKV GEMM
// out[t, j] = sum_c x[b,c,t] * w_qkv[j,c];  write to (b,which,h,t,d)
__global__ __launch_bounds__(256) void qkv_gemm_k(const float* __restrict__ x,
                                                  const float* __restrict__ w,
                                                  float* __restrict__ qkv) {
    __shared__ float Xs[32][64];   // [c][t]  (reads at uniform c -> no pad needed)
    __shared__ float Ws[32][65];   // [c][j]  padded
    int tid = threadIdx.x;
    int t0 = blockIdx.x * 64;
    int j0 = blockIdx.y * 64;
    int b  = blockIdx.z;
    int tx = tid & 15, ty = tid >> 4;   // tx -> j dim, ty -> t dim
    float acc[4][4] = {};
    const float* xb = x + (size_t)b * CC * TT;
    for (int c0 = 0; c0 < CC; c0 += 32) {
        __syncthreads();
        {
            int tl = tid & 63, ccl = tid >> 6;
            for (int k = 0; k < 8; ++k)
                Xs[ccl + 4 * k][tl] = xb[(size_t)(c0 + ccl + 4 * k) * TT + t0 + tl];
            int cw = tid & 31, jl = tid >> 5;
            for (int k = 0; k < 8; ++k)
                Ws[cw][jl + 8 * k] = w[(size_t)(j0 + jl + 8 * k) * CC + c0 + cw];
        }
        __syncthreads();
        for (int c2 = 0; c2 < 32; ++c2) {
            float a[4], bv[4];
            for (int i = 0; i < 4; ++i) a[i] = Xs[c2][ty + 16 * i];
            for (int j = 0; j < 4; ++j) bv[j] = Ws[c2][tx + 16 * j];
            for (int i = 0; i < 4; ++i)
                for (int j = 0; j < 4; ++j)
                    acc[i][j] += a[i] * bv[j];
        }
    }
    // j0 is a multiple of 64 -> whole block shares `which` and `h`
    int which = j0 >> 9;            // 0=q, 1=k, 2=v
    int h = (j0 & 511) >> 6;
    float* outb = qkv + ((size_t)((b * 3 + which) * HH + h)) * TT * DD;
    for (int i = 0; i < 4; ++i) {
        int t = t0 + ty + 16 * i;
        for (int j = 0; j < 4; ++j)
            outb[(size_t)t * DD + tx + 16 * j] = acc[i][j];
    }
}

// ---------------------------------------------------------------- attention
// flash-style over 32-key tiles; block = (b, h, 64 q rows)
__global__ __launch_bounds__(256) void attention_k(const float* __restrict__ qkv,
                                                   const float* __restrict__ biasb,
                                                   float* __restrict__ attn) {
    __shared__ float Qs[64][65];
    __shared__ float Ks[32][65];
    __shared__ float Vs[32][65];
    __shared__ float Ps[64][33];
    __shared__ float m_s[64], l_s[64], a_s[64];
    int tid = threadIdx.x;
    int q0 = blockIdx.x * 64;
    int h  = blockIdx.y;
    int b  = blockIdx.z;
    int tx = tid & 15, ty = tid >> 4;   // tx -> k/d dim, ty -> q dim
    const float* qb = qkv + ((size_t)((b * 3 + 0) * HH + h)) * TT * DD;
    const float* kb = qkv + ((size_t)((b * 3 + 1) * HH + h)) * TT * DD;
    const float* vb = qkv + ((size_t)((b * 3 + 2) * HH + h)) * TT * DD;
    {
        int d = tid & 63, r0 = tid >> 6;
        for (int k = 0; k < 16; ++k)
            Qs[r0 + 4 * k][d] = qb[(size_t)(q0 + r0 + 4 * k) * DD + d];
    }
    if (tid < 64) { m_s[tid] = -INFINITY; l_s[tid] = 0.f; }
    float O[4][4] = {};
    __syncthreads();
    for (int s0 = 0; s0 < TT; s0 += 32) {
        {
            int d = tid & 63, r0 = tid >> 6;
            for (int k = 0; k < 8; ++k) {
                Ks[r0 + 4 * k][d] = kb[(size_t)(s0 + r0 + 4 * k) * DD + d];
                Vs[r0 + 4 * k][d] = vb[(size_t)(s0 + r0 + 4 * k) * DD + d];
            }
        }
        __syncthreads();
        // S = Q K^T  (64q x 32k), each thread 4q x 2k
        float sreg[4][2] = {};
        for (int dd = 0; dd < 64; ++dd) {
            float qv[4], kv[2];
            for (int i = 0; i < 4; ++i) qv[i] = Qs[ty + 16 * i][dd];
            for (int j = 0; j < 2; ++j) kv[j] = Ks[tx + 16 * j][dd];
            for (int i = 0; i < 4; ++i)
                for (int j = 0; j < 2; ++j)
                    sreg[i][j] += qv[i] * kv[j];
        }
        float bv[2];
        for (int j = 0; j < 2; ++j) bv[j] = biasb[(size_t)b * TT + s0 + tx + 16 * j];
        for (int i = 0; i < 4; ++i)
            for (int j = 0; j < 2; ++j)
                Ps[ty + 16 * i][tx + 16 * j] = sreg[i][j] * SCALE + bv[j];
        __syncthreads();
        // online softmax, one thread per q row (wave 0)
        if (tid < 64) {
            float m_old = m_s[tid];
            float mx = m_old;
            for (int k = 0; k < 32; ++k) mx = fmaxf(mx, Ps[tid][k]);
            float alpha = __expf(m_old - mx);   // m_old=-inf -> 0
            float sum = 0.f;
            for (int k = 0; k < 32; ++k) {
                float p = __expf(Ps[tid][k] - mx);
                Ps[tid][k] = p;
                sum += p;
            }
            m_s[tid] = mx;
            l_s[tid] = l_s[tid] * alpha + sum;
            a_s[tid] = alpha;
        }
        __syncthreads();
        // rescale O, then O += P V  (64q x 64d), each thread 4q x 4d
        for (int i = 0; i < 4; ++i) {
            float al = a_s[ty + 16 * i];
            for (int j = 0; j < 4; ++j) O[i][j] *= al;
        }
        for (int kk = 0; kk < 32; ++kk) {
            float pv[4], vv[4];
            for (int i = 0; i < 4; ++i) pv[i] = Ps[ty + 16 * i][kk];
            for (int j = 0; j < 4; ++j) vv[j] = Vs[kk][tx + 16 * j];
            for (int i = 0; i < 4; ++i)
                for (int j = 0; j < 4; ++j)
                    O[i][j] += pv[i] * vv[j];
        }
        __syncthreads();
    }
    for (int i = 0; i < 4; ++i) {
        float inv = 1.f / l_s[ty + 16 * i];
        int t = q0 + ty + 16 * i;
        for (int j = 0; j < 4; ++j)
            attn[((size_t)b * TT + t) * CC + h * DD + tx + 16 * j] = O[i][j] * inv;
    }
}

// ---------------------------------------------------------------- out proj + bias + residual
__global__ __launch_bounds__(256) void out_proj_k(const float* __restrict__ attn,
                                                  const float* __restrict__ w,
                                                  const float* __restrict__ bout,
                                                  const float* __restrict__ x,
                                                  float* __restrict__ hbuf) {
    __shared__ float As[64][33];   // [t][c] padded
    __shared__ float Ws[32][65];   // [c][i] padded
    int tid = threadIdx.x;
    int t0 = blockIdx.x * 64;
    int i0 = blockIdx.y * 64;
    int b  = blockIdx.z;
    int tx = tid & 15, ty = tid >> 4;   // tx -> i dim, ty -> t dim
    float acc[4][4] = {};
    const float* ab = attn + (size_t)b * TT * CC;
    for (int c0 = 0; c0 < CC; c0 += 32) {
        __syncthreads();
        {
            int cw = tid & 31, rr = tid >> 5;
            for (int k = 0; k < 8; ++k)
                As[rr + 8 * k][cw] = ab[(size_t)(t0 + rr + 8 * k) * CC + c0 + cw];
            for (int k = 0; k < 8; ++k)
                Ws[cw][rr + 8 * k] = w[(size_t)(i0 + rr + 8 * k) * CC + c0 + cw];
        }
        __syncthreads();
        for (int c2 = 0; c2 < 32; ++c2) {
            float a[4], bv[4];
            for (int i = 0; i < 4; ++i) a[i] = As[ty + 16 * i][c2];
            for (int j = 0; j < 4; ++j) bv[j] = Ws[c2][tx + 16 * j];
            for (int i = 0; i < 4; ++i)
                for (int j = 0; j < 4; ++j)
                    acc[i][j] += a[i] * bv[j];
        }
    }
    float bo[4];
    for (int j = 0; j < 4; ++j) bo[j] = bout[i0 + tx + 16 * j];
    for (int i = 0; i < 4; ++i) {
        int t = t0 + ty + 16 * i;
        for (int j = 0; j < 4; ++j) {
            int ii = i0 + tx + 16 * j;
            float hv = acc[i][j] + bo[j] + x[((size_t)b * CC + ii) * TT + t];
            hbuf[((size_t)b * TT + t) * CC + ii] = hv;
        }
    }
}

// ---------------------------------------------------------------- LN stats (wave per row)
__global__ __launch_bounds__(256) void ln_stats_k(const float* __restrict__ hbuf,
                                                  float* __restrict__ mu,
                                                  float* __restrict__ rstd) {
    int tid = threadIdx.x;
    int lane = tid & 63, wid = tid >> 6;
    int row = blockIdx.x * 4 + wid;
    const float* hr = hbuf + (size_t)row * CC;
    float s = 0.f, sq = 0.f;
    for (int k = 0; k < CC / 64; ++k) {
        float v = hr[lane + 64 * k];
        s += v; sq += v * v;
    }
    for (int off = 32; off > 0; off >>= 1) {
        s  += __shfl_down(s, off);
        sq += __shfl_down(sq, off);
    }
    if (lane == 0) {
        float m = s / CC;
        float var = sq / CC - m * m;
        mu[row] = m;
        rstd[row] = rsqrtf(var + EPS);
    }
}

// ---------------------------------------------------------------- LN apply + transpose to (B,C,T)
__global__ __launch_bounds__(256) void ln_write_k(const float* __restrict__ hbuf,
                                                  const float* __restrict__ mu,
                                                  const float* __restrict__ rstd,
                                                  const float* __restrict__ gamma,
                                                  const float* __restrict__ beta,
                                                  float* __restrict__ out) {
    __shared__ float Ts[64][65];
    __shared__ float mus[64], rs[64];
    int tid = threadIdx.x;
    int t0 = blockIdx.x * 64, c0 = blockIdx.y * 64, b = blockIdx.z;
    if (tid < 64) {
        mus[tid] = mu[(size_t)b * TT + t0 + tid];
        rs[tid]  = rstd[(size_t)b * TT + t0 + tid];
    }
    __syncthreads();
    int cl = tid & 63, r0 = tid >> 6;
    float g = gamma[c0 + cl], be = beta[c0 + cl];
    for (int k = 0; k < 16; ++k) {
        int tl = r0 + 4 * k;
        float v = hbuf[((size_t)b * TT + t0 + tl) * CC + c0 + cl];
        Ts[tl][cl] = (v - mus[tl]) * rs[tl] * g + be;
    }
    __syncthreads();
    int tl2 = tid & 63;
    for (int k = 0; k < 16; ++k) {
        int c2 = r0 + 4 * k;
        out[((size_t)b * CC + c0 + c2) * TT + t0 + tl2] = Ts[tl2][c2];
    }
}

// ----------------------------------------------------------------
extern "C" void kernel_launch(void* const* d_in, const int* in_sizes, int n_in,
                              void* d_out, int out_size, void* d_ws, size_t ws_size,
                              hipStream_t stream) {
    const float* x      = (const float*)d_in[0];
    const float* sqi    = (const float*)d_in[1];
    const float* w_qkv  = (const float*)d_in[2];
    const float* w_out  = (const float*)d_in[3];
    const float* b_out  = (const float*)d_in[4];
    const float* w_conv = (const float*)d_in[5];
    const float* b_conv = (const float*)d_in[6];
    const float* gamma  = (const float*)d_in[7];
    const float* beta   = (const float*)d_in[8];
    float* out = (float*)d_out;

    float* qkvbuf = (float*)d_ws;                         // B*3*C*T
    float* attn   = qkvbuf + (size_t)BB * 3 * CC * TT;    // B*T*C
    float* biasb  = attn + (size_t)BB * TT * CC;          // B*T
    float* mu     = biasb + BB * TT;                      // B*T
    float* rstd   = mu + BB * TT;                         // B*T
    float* hbuf   = qkvbuf;                               // reuse (attention done)

    conv_bias_k<<<dim3((BB * TT) / 256), 256, 0, stream>>>(sqi, w_conv, b_conv, biasb);
    qkv_gemm_k<<<dim3(TT / 64, (3 * CC) / 64, BB), 256, 0, stream>>>(x, w_qkv, qkvbuf);
    attention_k<<<dim3(TT / 64, HH, BB), 256, 0, stream>>>(qkvbuf, biasb, attn);
    out_proj_k<<<dim3(TT / 64, CC / 64, BB), 256, 0, stream>>>(attn, w_out, b_out, x, hbuf);
    ln_stats_k<<<dim3((BB * TT) / 4), 256, 0, stream>>>(hbuf, mu, rstd);
    ln_write_k<<<dim3(TT / 64, CC / 64, BB), 256, 0, stream>>>(hbuf, mu, rstd, gamma, beta, out);
}

// Round 2
// 492.635 us; speedup vs baseline: 2.4496x; 2.4496x over previous
//
#include <hip/hip_runtime.h>
#include <math.h>

// Problem constants (LogitBiasedSelfAttention1D): B=4, C=512, T=2048, H=8, D=64
#define BB 4
#define CC 512
#define TT 2048
#define HH 8
#define DD 64
#define SCALE 0.125f
#define EPS 1e-5f

typedef __attribute__((ext_vector_type(8))) short bf16x8;   // 8 bf16 = 4 VGPRs (MFMA A/B frag)
typedef __attribute__((ext_vector_type(4))) float f32x4;    // MFMA C/D frag

__device__ inline ushort f2bf(float f) {           // RNE fp32 -> bf16
    unsigned int u = __builtin_bit_cast(unsigned int, f);
    u = (u + 0x7fff + ((u >> 16) & 1)) >> 16;
    return (ushort)u;
}

// ---------------------------------------------------------------- conv bias
__global__ void conv_bias_k(const float* __restrict__ sqi,
                            const float* __restrict__ wc,
                            const float* __restrict__ bc,
                            float* __restrict__ biasb) {
    int idx = blockIdx.x * 256 + threadIdx.x;
    if (idx >= BB * TT) return;
    int t = idx & (TT - 1);
    float l = (t > 0)      ? sqi[idx - 1] : 0.f;
    float m = sqi[idx];
    float r = (t < TT - 1) ? sqi[idx + 1] : 0.f;
    biasb[idx] = wc[0] * l + wc[1] * m + wc[2] * r + bc[0];
}

// ---------------------------------------------------------------- QKV GEMM (fp32 compute, bf16 out)
// q,k -> (b,h,t,d) d-contig; v -> (b,h,d,t) t-contig (pre-transposed for attention PV)
__global__ __launch_bounds__(256) void qkv_gemm_k(const float* __restrict__ x,
                                                  const float* __restrict__ w,
                                                  ushort* __restrict__ qkv) {
    __shared__ float Xs[32][64];   // [c][t]
    __shared__ float Ws[32][65];   // [c][j] padded
    __shared__ ushort Es[64 * 72]; // bf16 epilogue transpose tile, stride 72 (16B-mult)
    int tid = threadIdx.x;
    int t0 = blockIdx.x * 64;
    int j0 = blockIdx.y * 64;
    int b  = blockIdx.z;
    int tx = tid & 15, ty = tid >> 4;
    float acc[4][4] = {};
    const float* xb = x + (size_t)b * CC * TT;
    for (int c0 = 0; c0 < CC; c0 += 32) {
        __syncthreads();
        {
            int tl = tid & 63, ccl = tid >> 6;
            for (int k = 0; k < 8; ++k)
                Xs[ccl + 4 * k][tl] = xb[(size_t)(c0 + ccl + 4 * k) * TT + t0 + tl];
            int cw = tid & 31, jl = tid >> 5;
            for (int k = 0; k < 8; ++k)
                Ws[cw][jl + 8 * k] = w[(size_t)(j0 + jl + 8 * k) * CC + c0 + cw];
        }
        __syncthreads();
        for (int c2 = 0; c2 < 32; ++c2) {
            float a[4], bv[4];
            for (int i = 0; i < 4; ++i) a[i] = Xs[c2][ty + 16 * i];
            for (int j = 0; j < 4; ++j) bv[j] = Ws[c2][tx + 16 * j];
            for (int i = 0; i < 4; ++i)
                for (int j = 0; j < 4; ++j)
                    acc[i][j] += a[i] * bv[j];
        }
    }
    int which = j0 >> 9;            // 0=q,1=k,2=v
    int h = (j0 & 511) >> 6;
    if (which < 2) {                // Es[t][d]
        for (int i = 0; i < 4; ++i)
            for (int j = 0; j < 4; ++j)
                Es[(ty + 16 * i) * 72 + (tx + 16 * j)] = f2bf(acc[i][j]);
    } else {                        // Es[d][t]  (transpose for v)
        for (int i = 0; i < 4; ++i)
            for (int j = 0; j < 4; ++j)
                Es[(tx + 16 * j) * 72 + (ty + 16 * i)] = f2bf(acc[i][j]);
    }
    __syncthreads();
    ushort* outb = qkv + ((size_t)((b * 3 + which) * HH + h)) * TT * DD;
    for (int it = 0; it < 2; ++it) {
        int f = it * 256 + tid;     // 0..511 chunks of 8 bf16
        int row = f >> 3, ch = f & 7;
        uint4 val = *(const uint4*)&Es[row * 72 + ch * 8];
        if (which < 2)
            *(uint4*)(outb + (size_t)(t0 + row) * DD + ch * 8) = val;      // row=t, coalesced
        else
            *(uint4*)(outb + (size_t)row * TT + t0 + ch * 8) = val;        // row=d, coalesced in t
    }
}

// ---------------------------------------------------------------- attention (bf16 MFMA, flash-style)
// block = (64 q rows, h, b), 4 waves; wave w owns q rows [16w,16w+16)
// S^T = K·Q^T (16x16x32 MFMA), online softmax in registers (col=q per lane),
// P -> LDS bf16 (per-wave rows), O^T += Vt·P
__global__ __launch_bounds__(256, 4) void attention_k(const ushort* __restrict__ qkv,
                                                      const float* __restrict__ biasb,
                                                      float* __restrict__ attn) {
    __shared__ ushort Qf[4096];     // 64q x 64d in fragment order
    __shared__ ushort Kf[4096];     // 64k x 64d in fragment order
    __shared__ ushort Vf[4096];     // 64d x 64k (Vt) in fragment order
    __shared__ ushort Pq[64 * 72];  // P[q][key] bf16, stride 72
    __shared__ float bias_s[64];
    int tid = threadIdx.x;
    int lane = tid & 63, w = tid >> 6;
    int c = lane & 15, g = lane >> 4;       // c = q col, g = quad
    int q0 = blockIdx.x * 64, h = blockIdx.y, b = blockIdx.z;
    const ushort* qb = qkv + ((size_t)((b * 3 + 0) * HH + h)) * TT * DD;   // (t,d)
    const ushort* kb = qkv + ((size_t)((b * 3 + 1) * HH + h)) * TT * DD;   // (t,d)
    const ushort* vb = qkv + ((size_t)((b * 3 + 2) * HH + h)) * TT * DD;   // (d,t)

    // stage Q once: contiguous global load -> fragment-order LDS (bank-uniform b128 writes)
    for (int i = 0; i < 2; ++i) {
        int gg = i * 256 + tid;
        int row = gg >> 3, off8 = (gg & 7) * 8;
        int slot = ((gg >> 7) * 2 + ((gg >> 2) & 1)) * 64 + ((gg >> 3) & 15) + 16 * (gg & 3);
        ((uint4*)Qf)[slot] = *(const uint4*)(qb + (size_t)(q0 + row) * DD + off8);
    }
    __syncthreads();
    bf16x8 qfrag[2];                       // B-frag: Q[16w+c][ks*32 + g*8 + j], loop-invariant
    for (int ks = 0; ks < 2; ++ks)
        qfrag[ks] = *(const bf16x8*)&Qf[((w * 2 + ks) * 64 + lane) * 8];

    float m_run = -INFINITY, l_run = 0.f;
    f32x4 oacc[4];
    for (int dt = 0; dt < 4; ++dt) oacc[dt] = (f32x4){0.f, 0.f, 0.f, 0.f};
    int qrow = 16 * w + c;

    for (int s0 = 0; s0 < TT; s0 += 64) {
        __syncthreads();               // protect Kf/Vf from overwrite while in use
        for (int i = 0; i < 2; ++i) {  // stage K tile
            int gg = i * 256 + tid;
            int row = gg >> 3, off8 = (gg & 7) * 8;
            int slot = ((gg >> 7) * 2 + ((gg >> 2) & 1)) * 64 + ((gg >> 3) & 15) + 16 * (gg & 3);
            ((uint4*)Kf)[slot] = *(const uint4*)(kb + (size_t)(s0 + row) * DD + off8);
        }
        for (int i = 0; i < 2; ++i) {  // stage Vt tile (row=d, col=key)
            int gg = i * 256 + tid;
            int row = gg >> 3, off8 = (gg & 7) * 8;
            int slot = ((gg >> 7) * 2 + ((gg >> 2) & 1)) * 64 + ((gg >> 3) & 15) + 16 * (gg & 3);
            ((uint4*)Vf)[slot] = *(const uint4*)(vb + (size_t)row * TT + s0 + off8);
        }
        if (tid < 64) bias_s[tid] = biasb[(size_t)b * TT + s0 + tid];
        __syncthreads();

        // S^T (64 keys x 16 q): A = K frag (mt,ks), B = qfrag[ks]
        f32x4 st[4];
        for (int mt = 0; mt < 4; ++mt) {
            f32x4 acc = (f32x4){0.f, 0.f, 0.f, 0.f};
            for (int ks = 0; ks < 2; ++ks) {
                bf16x8 a = *(const bf16x8*)&Kf[((mt * 2 + ks) * 64 + lane) * 8];
                acc = __builtin_amdgcn_mfma_f32_16x16x32_bf16(a, qfrag[ks], acc, 0, 0, 0);
            }
            st[mt] = acc;
        }
        // scale + key bias; tile max (key = mt*16 + g*4 + r, q = c)
        float tmax = -INFINITY;
        for (int mt = 0; mt < 4; ++mt) {
            f32x4 bv = *(const f32x4*)&bias_s[mt * 16 + g * 4];   // broadcast across q lanes
            for (int r = 0; r < 4; ++r) {
                float s = st[mt][r] * SCALE + bv[r];
                st[mt][r] = s;
                tmax = fmaxf(tmax, s);
            }
        }
        tmax = fmaxf(tmax, __shfl_xor(tmax, 16));
        tmax = fmaxf(tmax, __shfl_xor(tmax, 32));
        float m_new = fmaxf(m_run, tmax);
        float alpha = __expf(m_run - m_new);   // first tile: exp(-inf)=0
        float rsum = 0.f;
        for (int mt = 0; mt < 4; ++mt)
            for (int r = 0; r < 4; ++r) {
                float p = __expf(st[mt][r] - m_new);
                st[mt][r] = p;
                rsum += p;
            }
        rsum += __shfl_xor(rsum, 16);
        rsum += __shfl_xor(rsum, 32);
        l_run = l_run * alpha + rsum;
        m_run = m_new;

        // P -> LDS (own rows only; no barrier needed)
        for (int mt = 0; mt < 4; ++mt) {
            ushort4 pk;
            pk.x = f2bf(st[mt][0]); pk.y = f2bf(st[mt][1]);
            pk.z = f2bf(st[mt][2]); pk.w = f2bf(st[mt][3]);
            *(ushort4*)&Pq[qrow * 72 + mt * 16 + g * 4] = pk;
        }
        // O^T += Vt · P : A = Vf frag (dt,ks), B = P[16w+c][ks*32+g*8..]
        bf16x8 pb[2];
        for (int ks = 0; ks < 2; ++ks)
            pb[ks] = *(const bf16x8*)&Pq[qrow * 72 + ks * 32 + g * 8];
        for (int dt = 0; dt < 4; ++dt) {
            f32x4 acc = oacc[dt];
            for (int r = 0; r < 4; ++r) acc[r] *= alpha;
            for (int ks = 0; ks < 2; ++ks) {
                bf16x8 a = *(const bf16x8*)&Vf[((dt * 2 + ks) * 64 + lane) * 8];
                acc = __builtin_amdgcn_mfma_f32_16x16x32_bf16(a, pb[ks], acc, 0, 0, 0);
            }
            oacc[dt] = acc;
        }
    }
    // epilogue: O^T[d][q] / l  -> attn[(b,t,c)] fp32; lane: q=c (t), d = dt*16+g*4+r
    float inv = 1.f / l_run;
    int t = q0 + 16 * w + c;
    float* ob = attn + ((size_t)b * TT + t) * CC + h * DD;
    for (int dt = 0; dt < 4; ++dt) {
        f32x4 o = oacc[dt];
        for (int r = 0; r < 4; ++r) o[r] *= inv;
        *(f32x4*)(ob + dt * 16 + g * 4) = o;
    }
}

// ---------------------------------------------------------------- out proj + bias + residual
__global__ __launch_bounds__(256) void out_proj_k(const float* __restrict__ attn,
                                                  const float* __restrict__ w,
                                                  const float* __restrict__ bout,
                                                  const float* __restrict__ x,
                                                  float* __restrict__ hbuf) {
    __shared__ float As[64][33];
    __shared__ float Ws[32][65];
    int tid = threadIdx.x;
    int t0 = blockIdx.x * 64;
    int i0 = blockIdx.y * 64;
    int b  = blockIdx.z;
    int tx = tid & 15, ty = tid >> 4;
    float acc[4][4] = {};
    const float* ab = attn + (size_t)b * TT * CC;
    for (int c0 = 0; c0 < CC; c0 += 32) {
        __syncthreads();
        {
            int cw = tid & 31, rr = tid >> 5;
            for (int k = 0; k < 8; ++k)
                As[rr + 8 * k][cw] = ab[(size_t)(t0 + rr + 8 * k) * CC + c0 + cw];
            for (int k = 0; k < 8; ++k)
                Ws[cw][rr + 8 * k] = w[(size_t)(i0 + rr + 8 * k) * CC + c0 + cw];
        }
        __syncthreads();
        for (int c2 = 0; c2 < 32; ++c2) {
            float a[4], bv[4];
            for (int i = 0; i < 4; ++i) a[i] = As[ty + 16 * i][c2];
            for (int j = 0; j < 4; ++j) bv[j] = Ws[c2][tx + 16 * j];
            for (int i = 0; i < 4; ++i)
                for (int j = 0; j < 4; ++j)
                    acc[i][j] += a[i] * bv[j];
        }
    }
    float bo[4];
    for (int j = 0; j < 4; ++j) bo[j] = bout[i0 + tx + 16 * j];
    for (int i = 0; i < 4; ++i) {
        int t = t0 + ty + 16 * i;
        for (int j = 0; j < 4; ++j) {
            int ii = i0 + tx + 16 * j;
            float hv = acc[i][j] + bo[j] + x[((size_t)b * CC + ii) * TT + t];
            hbuf[((size_t)b * TT + t) * CC + ii] = hv;
        }
    }
}

// ---------------------------------------------------------------- LN stats (wave per row)
__global__ __launch_bounds__(256) void ln_stats_k(const float* __restrict__ hbuf,
                                                  float* __restrict__ mu,
                                                  float* __restrict__ rstd) {
    int tid = threadIdx.x;
    int lane = tid & 63, wid = tid >> 6;
    int row = blockIdx.x * 4 + wid;
    const float* hr = hbuf + (size_t)row * CC;
    float s = 0.f, sq = 0.f;
    for (int k = 0; k < CC / 64; ++k) {
        float v = hr[lane + 64 * k];
        s += v; sq += v * v;
    }
    for (int off = 32; off > 0; off >>= 1) {
        s  += __shfl_down(s, off);
        sq += __shfl_down(sq, off);
    }
    if (lane == 0) {
        float m = s / CC;
        float var = sq / CC - m * m;
        mu[row] = m;
        rstd[row] = rsqrtf(var + EPS);
    }
}

// ---------------------------------------------------------------- LN apply + transpose to (B,C,T)
__global__ __launch_bounds__(256) void ln_write_k(const float* __restrict__ hbuf,
                                                  const float* __restrict__ mu,
                                                  const float* __restrict__ rstd,
                                                  const float* __restrict__ gamma,
                                                  const float* __restrict__ beta,
                                                  float* __restrict__ out) {
    __shared__ float Ts[64][65];
    __shared__ float mus[64], rs[64];
    int tid = threadIdx.x;
    int t0 = blockIdx.x * 64, c0 = blockIdx.y * 64, b = blockIdx.z;
    if (tid < 64) {
        mus[tid] = mu[(size_t)b * TT + t0 + tid];
        rs[tid]  = rstd[(size_t)b * TT + t0 + tid];
    }
    __syncthreads();
    int cl = tid & 63, r0 = tid >> 6;
    float g = gamma[c0 + cl], be = beta[c0 + cl];
    for (int k = 0; k < 16; ++k) {
        int tl = r0 + 4 * k;
        float v = hbuf[((size_t)b * TT + t0 + tl) * CC + c0 + cl];
        Ts[tl][cl] = (v - mus[tl]) * rs[tl] * g + be;
    }
    __syncthreads();
    int tl2 = tid & 63;
    for (int k = 0; k < 16; ++k) {
        int c2 = r0 + 4 * k;
        out[((size_t)b * CC + c0 + c2) * TT + t0 + tl2] = Ts[tl2][c2];
    }
}

// ----------------------------------------------------------------
extern "C" void kernel_launch(void* const* d_in, const int* in_sizes, int n_in,
                              void* d_out, int out_size, void* d_ws, size_t ws_size,
                              hipStream_t stream) {
    const float* x      = (const float*)d_in[0];
    const float* sqi    = (const float*)d_in[1];
    const float* w_qkv  = (const float*)d_in[2];
    const float* w_out  = (const float*)d_in[3];
    const float* b_out  = (const float*)d_in[4];
    const float* w_conv = (const float*)d_in[5];
    const float* b_conv = (const float*)d_in[6];
    const float* gamma  = (const float*)d_in[7];
    const float* beta   = (const float*)d_in[8];
    float* out = (float*)d_out;

    ushort* qkvbuf = (ushort*)d_ws;                            // B*3*C*T bf16 (25.2 MB)
    float*  attn   = (float*)(qkvbuf + (size_t)BB * 3 * CC * TT);  // B*T*C fp32 (16.8 MB)
    float*  biasb  = attn + (size_t)BB * TT * CC;              // B*T
    float*  mu     = biasb + BB * TT;
    float*  rstd   = mu + BB * TT;
    float*  hbuf   = (float*)d_ws;                             // reuse qkv region post-attention

    conv_bias_k<<<dim3((BB * TT) / 256), 256, 0, stream>>>(sqi, w_conv, b_conv, biasb);
    qkv_gemm_k<<<dim3(TT / 64, (3 * CC) / 64, BB), 256, 0, stream>>>(x, w_qkv, qkvbuf);
    attention_k<<<dim3(TT / 64, HH, BB), 256, 0, stream>>>(qkvbuf, biasb, attn);
    out_proj_k<<<dim3(TT / 64, CC / 64, BB), 256, 0, stream>>>(attn, w_out, b_out, x, hbuf);
    ln_stats_k<<<dim3((BB * TT) / 4), 256, 0, stream>>>(hbuf, mu, rstd);
    ln_write_k<<<dim3(TT / 64, CC / 64, BB), 256, 0, stream>>>(hbuf, mu, rstd, gamma, beta, out);
}

// Round 3
// 267.094 us; speedup vs baseline: 4.5181x; 1.8444x over previous
//
#include <hip/hip_runtime.h>
#include <math.h>

// Problem constants (LogitBiasedSelfAttention1D): B=4, C=512, T=2048, H=8, D=64
#define BB 4
#define CC 512
#define TT 2048
#define HH 8
#define DD 64
#define SCALE 0.125f
#define EPS 1e-5f

typedef __attribute__((ext_vector_type(8))) short bf16x8;   // 8 bf16 = 4 VGPRs (MFMA A/B frag)
typedef __attribute__((ext_vector_type(4))) float f32x4;    // MFMA C/D frag

__device__ inline ushort f2bf(float f) {           // RNE fp32 -> bf16
    unsigned int u = __builtin_bit_cast(unsigned int, f);
    u = (u + 0x7fff + ((u >> 16) & 1)) >> 16;
    return (ushort)u;
}
__device__ inline float bf2f(ushort u) {
    unsigned int v = ((unsigned int)u) << 16;
    return __builtin_bit_cast(float, v);
}

// ---------------------------------------------------------------- conv bias
__global__ void conv_bias_k(const float* __restrict__ sqi,
                            const float* __restrict__ wc,
                            const float* __restrict__ bc,
                            float* __restrict__ biasb) {
    int idx = blockIdx.x * 256 + threadIdx.x;
    if (idx >= BB * TT) return;
    int t = idx & (TT - 1);
    float l = (t > 0)      ? sqi[idx - 1] : 0.f;
    float m = sqi[idx];
    float r = (t < TT - 1) ? sqi[idx + 1] : 0.f;
    biasb[idx] = wc[0] * l + wc[1] * m + wc[2] * r + bc[0];
}

// ---------------------------------------------------------------- weight cast fp32->bf16
__global__ void w_cast_k(const float* __restrict__ wq, const float* __restrict__ wo,
                         ushort* __restrict__ wqb, ushort* __restrict__ wob) {
    int idx = blockIdx.x * 256 + threadIdx.x;   // grid covers 3*C*C + C*C
    if (idx < 3 * CC * CC) wqb[idx] = f2bf(wq[idx]);
    else                   wob[idx - 3 * CC * CC] = f2bf(wo[idx - 3 * CC * CC]);
}

// ---------------------------------------------------------------- x (b,c,t) fp32 -> xt (b,t,c) bf16
__global__ __launch_bounds__(256) void xt_cast_k(const float* __restrict__ x,
                                                 ushort* __restrict__ xt) {
    __shared__ float Ts[64][65];
    int tid = threadIdx.x;
    int t0 = blockIdx.x * 64, c0 = blockIdx.y * 64, b = blockIdx.z;
    int tl = tid & 63, r0 = tid >> 6;
    for (int k = 0; k < 16; ++k) {
        int cr = r0 * 16 + k;
        Ts[cr][tl] = x[((size_t)b * CC + c0 + cr) * TT + t0 + tl];  // coalesced in t
    }
    __syncthreads();
    int cl = tid & 63;
    for (int k = 0; k < 16; ++k) {
        int tw = r0 * 16 + k;
        xt[((size_t)b * TT + t0 + tw) * CC + c0 + cl] = f2bf(Ts[cl][tw]);  // coalesced in c
    }
}

// ---------------------------------------------------------------- QKV GEMM (bf16 MFMA)
// C[t][j] = sum_c xt[b,t,c] * wqb[j,c]; q,k -> (b,h,t,d); v -> (b,h,d,t) via transposed LDS tile
__global__ __launch_bounds__(256) void qkv_mfma_k(const ushort* __restrict__ xt,
                                                  const ushort* __restrict__ wqb,
                                                  ushort* __restrict__ qkv) {
    __shared__ ushort LDSb[17408];          // 34.8KB: As[0..8192) Bs[8192..16384); epilogue 128x136
    ushort* As = LDSb;
    ushort* Bs = LDSb + 8192;
    int tid = threadIdx.x;
    int lane = tid & 63, w = tid >> 6;
    int wm = w & 1, wn = w >> 1;
    int m0 = blockIdx.x * 128;              // t
    int j0 = blockIdx.y * 128;              // output channel
    int b  = blockIdx.z;
    const ushort* Abase = xt + ((size_t)b * TT + m0) * CC;
    const ushort* Bbase = wqb + (size_t)j0 * CC;
    f32x4 acc[4][4];
    for (int mt = 0; mt < 4; ++mt)
        for (int nt = 0; nt < 4; ++nt)
            acc[mt][nt] = (f32x4){0.f, 0.f, 0.f, 0.f};

    for (int k0 = 0; k0 < CC; k0 += 64) {
        __syncthreads();
#pragma unroll
        for (int i = 0; i < 4; ++i) {
            int gg = i * 256 + tid;
            int row = gg >> 3, ch = gg & 7;
            int slot = ((row >> 4) * 2 + (ch >> 2)) * 64 + (row & 15) + 16 * (ch & 3);
            ((uint4*)As)[slot] = *(const uint4*)(Abase + (size_t)row * CC + k0 + ch * 8);
            ((uint4*)Bs)[slot] = *(const uint4*)(Bbase + (size_t)row * CC + k0 + ch * 8);
        }
        __syncthreads();
#pragma unroll
        for (int ks = 0; ks < 2; ++ks) {
            bf16x8 af[4], bfr[4];
#pragma unroll
            for (int mt = 0; mt < 4; ++mt)
                af[mt] = *(const bf16x8*)&As[(((wm * 4 + mt) * 2 + ks) * 64 + lane) * 8];
#pragma unroll
            for (int nt = 0; nt < 4; ++nt)
                bfr[nt] = *(const bf16x8*)&Bs[(((wn * 4 + nt) * 2 + ks) * 64 + lane) * 8];
#pragma unroll
            for (int mt = 0; mt < 4; ++mt)
#pragma unroll
                for (int nt = 0; nt < 4; ++nt)
                    acc[mt][nt] = __builtin_amdgcn_mfma_f32_16x16x32_bf16(af[mt], bfr[nt], acc[mt][nt], 0, 0, 0);
        }
    }
    // epilogue via LDS bounce (stride 136 ushorts = 16B multiple)
    int which = j0 >> 9;                    // 0=q,1=k,2=v (128-tiles never straddle)
    int c = lane & 15, g = lane >> 4;
    __syncthreads();
    if (which < 2) {                        // [row=t][col=j]
#pragma unroll
        for (int mt = 0; mt < 4; ++mt)
            for (int r = 0; r < 4; ++r) {
                int row = wm * 64 + mt * 16 + g * 4 + r;
                for (int nt = 0; nt < 4; ++nt)
                    LDSb[row * 136 + wn * 64 + nt * 16 + c] = f2bf(acc[mt][nt][r]);
            }
    } else {                                // transposed: [col=j][row=t]
#pragma unroll
        for (int mt = 0; mt < 4; ++mt)
            for (int r = 0; r < 4; ++r) {
                int row = wm * 64 + mt * 16 + g * 4 + r;
                for (int nt = 0; nt < 4; ++nt)
                    LDSb[(wn * 64 + nt * 16 + c) * 136 + row] = f2bf(acc[mt][nt][r]);
            }
    }
    __syncthreads();
    if (which < 2) {
        ushort* base = qkv + (size_t)(b * 3 + which) * HH * TT * DD;
#pragma unroll
        for (int it = 0; it < 8; ++it) {
            int f = it * 256 + tid;
            int row = f >> 4, ch = f & 15;          // row=t-local, ch: 8-col chunk
            uint4 val = *(const uint4*)&LDSb[row * 136 + ch * 8];
            int jj = (j0 & 511) + ch * 8;
            int h = jj >> 6, d = jj & 63;
            *(uint4*)(base + ((size_t)h * TT + m0 + row) * DD + d) = val;
        }
    } else {
        ushort* base = qkv + (size_t)(b * 3 + 2) * HH * TT * DD;
#pragma unroll
        for (int it = 0; it < 8; ++it) {
            int f = it * 256 + tid;
            int drow = f >> 4, tch = f & 15;        // drow=j-local, tch: 8-t chunk
            uint4 val = *(const uint4*)&LDSb[drow * 136 + tch * 8];
            int jj = (j0 & 511) + drow;
            int h = jj >> 6, d = jj & 63;
            *(uint4*)(base + ((size_t)h * DD + d) * TT + m0 + tch * 8) = val;
        }
    }
}

// ---------------------------------------------------------------- attention (bf16 MFMA, flash-style)
__global__ __launch_bounds__(256, 4) void attention_k(const ushort* __restrict__ qkv,
                                                      const float* __restrict__ biasb,
                                                      ushort* __restrict__ attnb) {
    __shared__ ushort Qf[4096];
    __shared__ ushort Kf[4096];
    __shared__ ushort Vf[4096];
    __shared__ ushort Pq[64 * 72];
    __shared__ float bias_s[64];
    int tid = threadIdx.x;
    int lane = tid & 63, w = tid >> 6;
    int c = lane & 15, g = lane >> 4;
    int q0 = blockIdx.x * 64, h = blockIdx.y, b = blockIdx.z;
    const ushort* qb = qkv + ((size_t)((b * 3 + 0) * HH + h)) * TT * DD;   // (t,d)
    const ushort* kb = qkv + ((size_t)((b * 3 + 1) * HH + h)) * TT * DD;   // (t,d)
    const ushort* vb = qkv + ((size_t)((b * 3 + 2) * HH + h)) * TT * DD;   // (d,t)

    for (int i = 0; i < 2; ++i) {
        int gg = i * 256 + tid;
        int row = gg >> 3, off8 = (gg & 7) * 8;
        int slot = ((gg >> 7) * 2 + ((gg >> 2) & 1)) * 64 + ((gg >> 3) & 15) + 16 * (gg & 3);
        ((uint4*)Qf)[slot] = *(const uint4*)(qb + (size_t)(q0 + row) * DD + off8);
    }
    __syncthreads();
    bf16x8 qfrag[2];
    for (int ks = 0; ks < 2; ++ks)
        qfrag[ks] = *(const bf16x8*)&Qf[((w * 2 + ks) * 64 + lane) * 8];

    float m_run = -INFINITY, l_run = 0.f;
    f32x4 oacc[4];
    for (int dt = 0; dt < 4; ++dt) oacc[dt] = (f32x4){0.f, 0.f, 0.f, 0.f};
    int qrow = 16 * w + c;

    for (int s0 = 0; s0 < TT; s0 += 64) {
        __syncthreads();
        for (int i = 0; i < 2; ++i) {
            int gg = i * 256 + tid;
            int row = gg >> 3, off8 = (gg & 7) * 8;
            int slot = ((gg >> 7) * 2 + ((gg >> 2) & 1)) * 64 + ((gg >> 3) & 15) + 16 * (gg & 3);
            ((uint4*)Kf)[slot] = *(const uint4*)(kb + (size_t)(s0 + row) * DD + off8);
        }
        for (int i = 0; i < 2; ++i) {
            int gg = i * 256 + tid;
            int row = gg >> 3, off8 = (gg & 7) * 8;
            int slot = ((gg >> 7) * 2 + ((gg >> 2) & 1)) * 64 + ((gg >> 3) & 15) + 16 * (gg & 3);
            ((uint4*)Vf)[slot] = *(const uint4*)(vb + (size_t)row * TT + s0 + off8);
        }
        if (tid < 64) bias_s[tid] = biasb[(size_t)b * TT + s0 + tid];
        __syncthreads();

        f32x4 st[4];
        for (int mt = 0; mt < 4; ++mt) {
            f32x4 acc = (f32x4){0.f, 0.f, 0.f, 0.f};
            for (int ks = 0; ks < 2; ++ks) {
                bf16x8 a = *(const bf16x8*)&Kf[((mt * 2 + ks) * 64 + lane) * 8];
                acc = __builtin_amdgcn_mfma_f32_16x16x32_bf16(a, qfrag[ks], acc, 0, 0, 0);
            }
            st[mt] = acc;
        }
        float tmax = -INFINITY;
        for (int mt = 0; mt < 4; ++mt) {
            f32x4 bv = *(const f32x4*)&bias_s[mt * 16 + g * 4];
            for (int r = 0; r < 4; ++r) {
                float s = st[mt][r] * SCALE + bv[r];
                st[mt][r] = s;
                tmax = fmaxf(tmax, s);
            }
        }
        tmax = fmaxf(tmax, __shfl_xor(tmax, 16));
        tmax = fmaxf(tmax, __shfl_xor(tmax, 32));
        float m_new = fmaxf(m_run, tmax);
        float alpha = __expf(m_run - m_new);
        float rsum = 0.f;
        for (int mt = 0; mt < 4; ++mt)
            for (int r = 0; r < 4; ++r) {
                float p = __expf(st[mt][r] - m_new);
                st[mt][r] = p;
                rsum += p;
            }
        rsum += __shfl_xor(rsum, 16);
        rsum += __shfl_xor(rsum, 32);
        l_run = l_run * alpha + rsum;
        m_run = m_new;

        for (int mt = 0; mt < 4; ++mt) {
            ushort4 pk;
            pk.x = f2bf(st[mt][0]); pk.y = f2bf(st[mt][1]);
            pk.z = f2bf(st[mt][2]); pk.w = f2bf(st[mt][3]);
            *(ushort4*)&Pq[qrow * 72 + mt * 16 + g * 4] = pk;
        }
        bf16x8 pb[2];
        for (int ks = 0; ks < 2; ++ks)
            pb[ks] = *(const bf16x8*)&Pq[qrow * 72 + ks * 32 + g * 8];
        for (int dt = 0; dt < 4; ++dt) {
            f32x4 acc = oacc[dt];
            for (int r = 0; r < 4; ++r) acc[r] *= alpha;
            for (int ks = 0; ks < 2; ++ks) {
                bf16x8 a = *(const bf16x8*)&Vf[((dt * 2 + ks) * 64 + lane) * 8];
                acc = __builtin_amdgcn_mfma_f32_16x16x32_bf16(a, pb[ks], acc, 0, 0, 0);
            }
            oacc[dt] = acc;
        }
    }
    float inv = 1.f / l_run;
    int t = q0 + 16 * w + c;
    ushort* ob = attnb + ((size_t)b * TT + t) * CC + h * DD;
    for (int dt = 0; dt < 4; ++dt) {
        ushort4 pk;
        pk.x = f2bf(oacc[dt][0] * inv); pk.y = f2bf(oacc[dt][1] * inv);
        pk.z = f2bf(oacc[dt][2] * inv); pk.w = f2bf(oacc[dt][3] * inv);
        *(ushort4*)(ob + dt * 16 + g * 4) = pk;
    }
}

// ---------------------------------------------------------------- out proj (bf16 MFMA) + bias + residual
__global__ __launch_bounds__(256) void out_proj_mfma_k(const ushort* __restrict__ attnb,
                                                       const ushort* __restrict__ wob,
                                                       const float* __restrict__ bout,
                                                       const ushort* __restrict__ xt,
                                                       float* __restrict__ hbuf) {
    __shared__ ushort As[8192];
    __shared__ ushort Bs[8192];
    int tid = threadIdx.x;
    int lane = tid & 63, w = tid >> 6;
    int wm = w & 1, wn = w >> 1;
    int m0 = blockIdx.x * 128;              // t
    int n0 = blockIdx.y * 128;              // output channel
    int b  = blockIdx.z;
    const ushort* Abase = attnb + ((size_t)b * TT + m0) * CC;
    const ushort* Bbase = wob + (size_t)n0 * CC;
    f32x4 acc[4][4];
    for (int mt = 0; mt < 4; ++mt)
        for (int nt = 0; nt < 4; ++nt)
            acc[mt][nt] = (f32x4){0.f, 0.f, 0.f, 0.f};

    for (int k0 = 0; k0 < CC; k0 += 64) {
        __syncthreads();
#pragma unroll
        for (int i = 0; i < 4; ++i) {
            int gg = i * 256 + tid;
            int row = gg >> 3, ch = gg & 7;
            int slot = ((row >> 4) * 2 + (ch >> 2)) * 64 + (row & 15) + 16 * (ch & 3);
            ((uint4*)As)[slot] = *(const uint4*)(Abase + (size_t)row * CC + k0 + ch * 8);
            ((uint4*)Bs)[slot] = *(const uint4*)(Bbase + (size_t)row * CC + k0 + ch * 8);
        }
        __syncthreads();
#pragma unroll
        for (int ks = 0; ks < 2; ++ks) {
            bf16x8 af[4], bfr[4];
#pragma unroll
            for (int mt = 0; mt < 4; ++mt)
                af[mt] = *(const bf16x8*)&As[(((wm * 4 + mt) * 2 + ks) * 64 + lane) * 8];
#pragma unroll
            for (int nt = 0; nt < 4; ++nt)
                bfr[nt] = *(const bf16x8*)&Bs[(((wn * 4 + nt) * 2 + ks) * 64 + lane) * 8];
#pragma unroll
            for (int mt = 0; mt < 4; ++mt)
#pragma unroll
                for (int nt = 0; nt < 4; ++nt)
                    acc[mt][nt] = __builtin_amdgcn_mfma_f32_16x16x32_bf16(af[mt], bfr[nt], acc[mt][nt], 0, 0, 0);
        }
    }
    int c = lane & 15, g = lane >> 4;
    float bo[4];
    for (int nt = 0; nt < 4; ++nt) bo[nt] = bout[n0 + wn * 64 + nt * 16 + c];
#pragma unroll
    for (int mt = 0; mt < 4; ++mt)
        for (int r = 0; r < 4; ++r) {
            int t = m0 + wm * 64 + mt * 16 + g * 4 + r;
            float* hrow = hbuf + ((size_t)b * TT + t) * CC;
            const ushort* xr = xt + ((size_t)b * TT + t) * CC;
            for (int nt = 0; nt < 4; ++nt) {
                int i = n0 + wn * 64 + nt * 16 + c;
                hrow[i] = acc[mt][nt][r] + bo[nt] + bf2f(xr[i]);
            }
        }
}

// ---------------------------------------------------------------- LN stats (wave per row)
__global__ __launch_bounds__(256) void ln_stats_k(const float* __restrict__ hbuf,
                                                  float* __restrict__ mu,
                                                  float* __restrict__ rstd) {
    int tid = threadIdx.x;
    int lane = tid & 63, wid = tid >> 6;
    int row = blockIdx.x * 4 + wid;
    const float* hr = hbuf + (size_t)row * CC;
    float s = 0.f, sq = 0.f;
    for (int k = 0; k < CC / 64; ++k) {
        float v = hr[lane + 64 * k];
        s += v; sq += v * v;
    }
    for (int off = 32; off > 0; off >>= 1) {
        s  += __shfl_down(s, off);
        sq += __shfl_down(sq, off);
    }
    if (lane == 0) {
        float m = s / CC;
        float var = sq / CC - m * m;
        mu[row] = m;
        rstd[row] = rsqrtf(var + EPS);
    }
}

// ---------------------------------------------------------------- LN apply + transpose to (B,C,T)
__global__ __launch_bounds__(256) void ln_write_k(const float* __restrict__ hbuf,
                                                  const float* __restrict__ mu,
                                                  const float* __restrict__ rstd,
                                                  const float* __restrict__ gamma,
                                                  const float* __restrict__ beta,
                                                  float* __restrict__ out) {
    __shared__ float Ts[64][65];
    __shared__ float mus[64], rs[64];
    int tid = threadIdx.x;
    int t0 = blockIdx.x * 64, c0 = blockIdx.y * 64, b = blockIdx.z;
    if (tid < 64) {
        mus[tid] = mu[(size_t)b * TT + t0 + tid];
        rs[tid]  = rstd[(size_t)b * TT + t0 + tid];
    }
    __syncthreads();
    int cl = tid & 63, r0 = tid >> 6;
    float g = gamma[c0 + cl], be = beta[c0 + cl];
    for (int k = 0; k < 16; ++k) {
        int tl = r0 + 4 * k;
        float v = hbuf[((size_t)b * TT + t0 + tl) * CC + c0 + cl];
        Ts[tl][cl] = (v - mus[tl]) * rs[tl] * g + be;
    }
    __syncthreads();
    int tl2 = tid & 63;
    for (int k = 0; k < 16; ++k) {
        int c2 = r0 + 4 * k;
        out[((size_t)b * CC + c0 + c2) * TT + t0 + tl2] = Ts[tl2][c2];
    }
}

// ----------------------------------------------------------------
extern "C" void kernel_launch(void* const* d_in, const int* in_sizes, int n_in,
                              void* d_out, int out_size, void* d_ws, size_t ws_size,
                              hipStream_t stream) {
    const float* x      = (const float*)d_in[0];
    const float* sqi    = (const float*)d_in[1];
    const float* w_qkv  = (const float*)d_in[2];
    const float* w_out  = (const float*)d_in[3];
    const float* b_out  = (const float*)d_in[4];
    const float* w_conv = (const float*)d_in[5];
    const float* b_conv = (const float*)d_in[6];
    const float* gamma  = (const float*)d_in[7];
    const float* beta   = (const float*)d_in[8];
    float* out = (float*)d_out;

    ushort* qkvbuf = (ushort*)d_ws;                          // B*3*C*T bf16 (25.2MB)
    ushort* xt     = qkvbuf + (size_t)BB * 3 * CC * TT;      // B*T*C bf16 (8.4MB)
    ushort* attnb  = xt + (size_t)BB * TT * CC;              // B*T*C bf16 (8.4MB)
    ushort* wqb    = attnb + (size_t)BB * TT * CC;           // 3C*C bf16 (1.6MB)
    ushort* wob    = wqb + 3 * CC * CC;                      // C*C bf16 (0.5MB)
    float*  biasb  = (float*)(wob + CC * CC);                // B*T
    float*  mu     = biasb + BB * TT;
    float*  rstd   = mu + BB * TT;
    float*  hbuf   = (float*)d_ws;                           // reuse qkv region post-attention (16.8MB)

    conv_bias_k<<<dim3((BB * TT) / 256), 256, 0, stream>>>(sqi, w_conv, b_conv, biasb);
    w_cast_k<<<dim3((4 * CC * CC) / 256), 256, 0, stream>>>(w_qkv, w_out, wqb, wob);
    xt_cast_k<<<dim3(TT / 64, CC / 64, BB), 256, 0, stream>>>(x, xt);
    qkv_mfma_k<<<dim3(TT / 128, (3 * CC) / 128, BB), 256, 0, stream>>>(xt, wqb, qkvbuf);
    attention_k<<<dim3(TT / 64, HH, BB), 256, 0, stream>>>(qkvbuf, biasb, attnb);
    out_proj_mfma_k<<<dim3(TT / 128, CC / 128, BB), 256, 0, stream>>>(attnb, wob, b_out, xt, hbuf);
    ln_stats_k<<<dim3((BB * TT) / 4), 256, 0, stream>>>(hbuf, mu, rstd);
    ln_write_k<<<dim3(TT / 64, CC / 64, BB), 256, 0, stream>>>(hbuf, mu, rstd, gamma, beta, out);
}

// Round 4
// 228.204 us; speedup vs baseline: 5.2881x; 1.1704x over previous
//
#include <hip/hip_runtime.h>
#include <math.h>

// Problem constants (LogitBiasedSelfAttention1D): B=4, C=512, T=2048, H=8, D=64
#define BB 4
#define CC 512
#define TT 2048
#define HH 8
#define DD 64
#define SCALE 0.125f
#define EPS 1e-5f

typedef __attribute__((ext_vector_type(8))) short bf16x8;   // 8 bf16 = 4 VGPRs (MFMA A/B frag)
typedef __attribute__((ext_vector_type(4))) float f32x4;    // MFMA C/D frag

__device__ inline ushort f2bf(float f) {           // RNE fp32 -> bf16
    unsigned int u = __builtin_bit_cast(unsigned int, f);
    u = (u + 0x7fff + ((u >> 16) & 1)) >> 16;
    return (ushort)u;
}
__device__ inline float bf2f(ushort u) {
    unsigned int v = ((unsigned int)u) << 16;
    return __builtin_bit_cast(float, v);
}

// ---------------------------------------------------------------- conv bias
__global__ void conv_bias_k(const float* __restrict__ sqi,
                            const float* __restrict__ wc,
                            const float* __restrict__ bc,
                            float* __restrict__ biasb) {
    int idx = blockIdx.x * 256 + threadIdx.x;
    if (idx >= BB * TT) return;
    int t = idx & (TT - 1);
    float l = (t > 0)      ? sqi[idx - 1] : 0.f;
    float m = sqi[idx];
    float r = (t < TT - 1) ? sqi[idx + 1] : 0.f;
    biasb[idx] = wc[0] * l + wc[1] * m + wc[2] * r + bc[0];
}

// ---------------------------------------------------------------- weight cast fp32->bf16
__global__ void w_cast_k(const float* __restrict__ wq, const float* __restrict__ wo,
                         ushort* __restrict__ wqb, ushort* __restrict__ wob) {
    int idx = blockIdx.x * 256 + threadIdx.x;
    if (idx < 3 * CC * CC) wqb[idx] = f2bf(wq[idx]);
    else                   wob[idx - 3 * CC * CC] = f2bf(wo[idx - 3 * CC * CC]);
}

// ---------------------------------------------------------------- x (b,c,t) fp32 -> xt (b,t,c) bf16
__global__ __launch_bounds__(256) void xt_cast_k(const float* __restrict__ x,
                                                 ushort* __restrict__ xt) {
    __shared__ float Ts[64][65];
    int tid = threadIdx.x;
    int t0 = blockIdx.x * 64, c0 = blockIdx.y * 64, b = blockIdx.z;
    int tl = tid & 63, r0 = tid >> 6;
    for (int k = 0; k < 16; ++k) {
        int cr = r0 * 16 + k;
        Ts[cr][tl] = x[((size_t)b * CC + c0 + cr) * TT + t0 + tl];
    }
    __syncthreads();
    int cl = tid & 63;
    for (int k = 0; k < 16; ++k) {
        int tw = r0 * 16 + k;
        xt[((size_t)b * TT + t0 + tw) * CC + c0 + cl] = f2bf(Ts[cl][tw]);
    }
}

// ---------------------------------------------------------------- QKV GEMM (bf16 MFMA)
// C[t][j] = sum_c xt[b,t,c] * wqb[j,c]; q,k -> (b,h,t,d); v -> (b,h,d,t)
__global__ __launch_bounds__(256) void qkv_mfma_k(const ushort* __restrict__ xt,
                                                  const ushort* __restrict__ wqb,
                                                  ushort* __restrict__ qkv) {
    __shared__ ushort LDSb[17408];          // As[0..8192) Bs[8192..16384); epilogue 128x136
    ushort* As = LDSb;
    ushort* Bs = LDSb + 8192;
    int tid = threadIdx.x;
    int lane = tid & 63, w = tid >> 6;
    int wm = w & 1, wn = w >> 1;
    int m0 = blockIdx.x * 128;
    int j0 = blockIdx.y * 128;
    int b  = blockIdx.z;
    const ushort* Abase = xt + ((size_t)b * TT + m0) * CC;
    const ushort* Bbase = wqb + (size_t)j0 * CC;
    f32x4 acc[4][4];
    for (int mt = 0; mt < 4; ++mt)
        for (int nt = 0; nt < 4; ++nt)
            acc[mt][nt] = (f32x4){0.f, 0.f, 0.f, 0.f};

    for (int k0 = 0; k0 < CC; k0 += 64) {
        __syncthreads();
        // conflict-free staging: slot = i*64+lane (linear); lane fetches its fragment element
#pragma unroll
        for (int it = 0; it < 4; ++it) {
            int i = w * 4 + it;                       // 0..15
            int row = (i >> 1) * 16 + (lane & 15);    // tile row
            int ch  = (i & 1) * 4 + (lane >> 4);      // 16B chunk within row
            ((uint4*)As)[i * 64 + lane] = *(const uint4*)(Abase + (size_t)row * CC + k0 + ch * 8);
            ((uint4*)Bs)[i * 64 + lane] = *(const uint4*)(Bbase + (size_t)row * CC + k0 + ch * 8);
        }
        __syncthreads();
#pragma unroll
        for (int ks = 0; ks < 2; ++ks) {
            bf16x8 af[4], bfr[4];
#pragma unroll
            for (int mt = 0; mt < 4; ++mt)
                af[mt] = *(const bf16x8*)&As[(((wm * 4 + mt) * 2 + ks) * 64 + lane) * 8];
#pragma unroll
            for (int nt = 0; nt < 4; ++nt)
                bfr[nt] = *(const bf16x8*)&Bs[(((wn * 4 + nt) * 2 + ks) * 64 + lane) * 8];
#pragma unroll
            for (int mt = 0; mt < 4; ++mt)
#pragma unroll
                for (int nt = 0; nt < 4; ++nt)
                    acc[mt][nt] = __builtin_amdgcn_mfma_f32_16x16x32_bf16(af[mt], bfr[nt], acc[mt][nt], 0, 0, 0);
        }
    }
    int which = j0 >> 9;
    int c = lane & 15, g = lane >> 4;
    __syncthreads();
    if (which < 2) {
#pragma unroll
        for (int mt = 0; mt < 4; ++mt)
            for (int r = 0; r < 4; ++r) {
                int row = wm * 64 + mt * 16 + g * 4 + r;
                for (int nt = 0; nt < 4; ++nt)
                    LDSb[row * 136 + wn * 64 + nt * 16 + c] = f2bf(acc[mt][nt][r]);
            }
    } else {
#pragma unroll
        for (int mt = 0; mt < 4; ++mt)
            for (int r = 0; r < 4; ++r) {
                int row = wm * 64 + mt * 16 + g * 4 + r;
                for (int nt = 0; nt < 4; ++nt)
                    LDSb[(wn * 64 + nt * 16 + c) * 136 + row] = f2bf(acc[mt][nt][r]);
            }
    }
    __syncthreads();
    if (which < 2) {
        ushort* base = qkv + (size_t)(b * 3 + which) * HH * TT * DD;
#pragma unroll
        for (int it = 0; it < 8; ++it) {
            int f = it * 256 + tid;
            int row = f >> 4, ch = f & 15;
            uint4 val = *(const uint4*)&LDSb[row * 136 + ch * 8];
            int jj = (j0 & 511) + ch * 8;
            int h = jj >> 6, d = jj & 63;
            *(uint4*)(base + ((size_t)h * TT + m0 + row) * DD + d) = val;
        }
    } else {
        ushort* base = qkv + (size_t)(b * 3 + 2) * HH * TT * DD;
#pragma unroll
        for (int it = 0; it < 8; ++it) {
            int f = it * 256 + tid;
            int drow = f >> 4, tch = f & 15;
            uint4 val = *(const uint4*)&LDSb[drow * 136 + tch * 8];
            int jj = (j0 & 511) + drow;
            int h = jj >> 6, d = jj & 63;
            *(uint4*)(base + ((size_t)h * DD + d) * TT + m0 + tch * 8) = val;
        }
    }
}

// ---------------------------------------------------------------- attention (bf16 MFMA, flash-style)
// block = 128 q rows x (h,b); 4 waves, each owns q-tiles {w, w+4} (2 q-groups of 16)
__global__ __launch_bounds__(256, 2) void attention_k(const ushort* __restrict__ qkv,
                                                      const float* __restrict__ biasb,
                                                      ushort* __restrict__ attnb) {
    __shared__ ushort QP[9216];     // Q stage (128x64 = slots 0..1023), then P[128][72]
    __shared__ ushort Kf[4096];
    __shared__ ushort Vf[4096];
    __shared__ float bias_s[64];
    int tid = threadIdx.x;
    int lane = tid & 63, w = tid >> 6;
    int c = lane & 15, g = lane >> 4;
    int q0 = blockIdx.x * 128, h = blockIdx.y, b = blockIdx.z;
    const ushort* qb = qkv + ((size_t)((b * 3 + 0) * HH + h)) * TT * DD;   // (t,d)
    const ushort* kb = qkv + ((size_t)((b * 3 + 1) * HH + h)) * TT * DD;   // (t,d)
    const ushort* vb = qkv + ((size_t)((b * 3 + 2) * HH + h)) * TT * DD;   // (d,t)

    // stage Q (conflict-free linear slots)
#pragma unroll
    for (int it = 0; it < 4; ++it) {
        int i = w * 4 + it;                       // 0..15
        int row = (i >> 1) * 16 + c;
        int ch  = (i & 1) * 4 + g;
        ((uint4*)QP)[i * 64 + lane] = *(const uint4*)(qb + (size_t)(q0 + row) * DD + ch * 8);
    }
    __syncthreads();
    bf16x8 qfrag[2][2];
    for (int qg = 0; qg < 2; ++qg)
        for (int ks = 0; ks < 2; ++ks)
            qfrag[qg][ks] = *(const bf16x8*)&QP[(((qg * 4 + w) * 2 + ks) * 64 + lane) * 8];

    float m_run[2] = {-INFINITY, -INFINITY};
    float l_run[2] = {0.f, 0.f};
    f32x4 oacc[2][4];
    for (int qg = 0; qg < 2; ++qg)
        for (int dt = 0; dt < 4; ++dt) oacc[qg][dt] = (f32x4){0.f, 0.f, 0.f, 0.f};

    for (int s0 = 0; s0 < TT; s0 += 64) {
        __syncthreads();
#pragma unroll
        for (int it = 0; it < 2; ++it) {
            int i = w * 2 + it;                   // 0..7
            int row = (i >> 1) * 16 + c;
            int ch  = (i & 1) * 4 + g;
            ((uint4*)Kf)[i * 64 + lane] = *(const uint4*)(kb + (size_t)(s0 + row) * DD + ch * 8);
            ((uint4*)Vf)[i * 64 + lane] = *(const uint4*)(vb + (size_t)row * TT + s0 + ch * 8);
        }
        if (tid < 64) bias_s[tid] = biasb[(size_t)b * TT + s0 + tid];
        __syncthreads();

        bf16x8 kf[4][2];
#pragma unroll
        for (int mt = 0; mt < 4; ++mt)
            for (int ks = 0; ks < 2; ++ks)
                kf[mt][ks] = *(const bf16x8*)&Kf[((mt * 2 + ks) * 64 + lane) * 8];

        float alpha_q[2];
#pragma unroll
        for (int qg = 0; qg < 2; ++qg) {
            f32x4 st[4];
#pragma unroll
            for (int mt = 0; mt < 4; ++mt) {
                f32x4 acc = (f32x4){0.f, 0.f, 0.f, 0.f};
                for (int ks = 0; ks < 2; ++ks)
                    acc = __builtin_amdgcn_mfma_f32_16x16x32_bf16(kf[mt][ks], qfrag[qg][ks], acc, 0, 0, 0);
                st[mt] = acc;
            }
            float tmax = -INFINITY;
#pragma unroll
            for (int mt = 0; mt < 4; ++mt) {
                f32x4 bv = *(const f32x4*)&bias_s[mt * 16 + g * 4];
                for (int r = 0; r < 4; ++r) {
                    float s = st[mt][r] * SCALE + bv[r];
                    st[mt][r] = s;
                    tmax = fmaxf(tmax, s);
                }
            }
            tmax = fmaxf(tmax, __shfl_xor(tmax, 16));
            tmax = fmaxf(tmax, __shfl_xor(tmax, 32));
            float m_new = fmaxf(m_run[qg], tmax);
            float alpha = __expf(m_run[qg] - m_new);
            float rsum = 0.f;
#pragma unroll
            for (int mt = 0; mt < 4; ++mt)
                for (int r = 0; r < 4; ++r) {
                    float p = __expf(st[mt][r] - m_new);
                    st[mt][r] = p;
                    rsum += p;
                }
            rsum += __shfl_xor(rsum, 16);
            rsum += __shfl_xor(rsum, 32);
            l_run[qg] = l_run[qg] * alpha + rsum;
            m_run[qg] = m_new;
            alpha_q[qg] = alpha;

            int qrow = (qg * 4 + w) * 16 + c;
#pragma unroll
            for (int mt = 0; mt < 4; ++mt) {
                ushort4 pk;
                pk.x = f2bf(st[mt][0]); pk.y = f2bf(st[mt][1]);
                pk.z = f2bf(st[mt][2]); pk.w = f2bf(st[mt][3]);
                *(ushort4*)&QP[qrow * 72 + mt * 16 + g * 4] = pk;
            }
        }

        bf16x8 vf[4][2];
#pragma unroll
        for (int dt = 0; dt < 4; ++dt)
            for (int ks = 0; ks < 2; ++ks)
                vf[dt][ks] = *(const bf16x8*)&Vf[((dt * 2 + ks) * 64 + lane) * 8];

#pragma unroll
        for (int qg = 0; qg < 2; ++qg) {
            int qrow = (qg * 4 + w) * 16 + c;
            bf16x8 pb[2];
            for (int ks = 0; ks < 2; ++ks)
                pb[ks] = *(const bf16x8*)&QP[qrow * 72 + ks * 32 + g * 8];
            float al = alpha_q[qg];
#pragma unroll
            for (int dt = 0; dt < 4; ++dt) {
                f32x4 acc = oacc[qg][dt];
                for (int r = 0; r < 4; ++r) acc[r] *= al;
                for (int ks = 0; ks < 2; ++ks)
                    acc = __builtin_amdgcn_mfma_f32_16x16x32_bf16(vf[dt][ks], pb[ks], acc, 0, 0, 0);
                oacc[qg][dt] = acc;
            }
        }
    }
#pragma unroll
    for (int qg = 0; qg < 2; ++qg) {
        float inv = 1.f / l_run[qg];
        int t = q0 + (qg * 4 + w) * 16 + c;
        ushort* ob = attnb + ((size_t)b * TT + t) * CC + h * DD;
        for (int dt = 0; dt < 4; ++dt) {
            ushort4 pk;
            pk.x = f2bf(oacc[qg][dt][0] * inv); pk.y = f2bf(oacc[qg][dt][1] * inv);
            pk.z = f2bf(oacc[qg][dt][2] * inv); pk.w = f2bf(oacc[qg][dt][3] * inv);
            *(ushort4*)(ob + dt * 16 + g * 4) = pk;
        }
    }
}

// ---------------------------------------------------------------- out proj (bf16 MFMA) + bias + residual
__global__ __launch_bounds__(256) void out_proj_mfma_k(const ushort* __restrict__ attnb,
                                                       const ushort* __restrict__ wob,
                                                       const float* __restrict__ bout,
                                                       const ushort* __restrict__ xt,
                                                       float* __restrict__ hbuf) {
    __shared__ ushort As[8192];
    __shared__ ushort Bs[8192];
    int tid = threadIdx.x;
    int lane = tid & 63, w = tid >> 6;
    int wm = w & 1, wn = w >> 1;
    int m0 = blockIdx.x * 128;
    int n0 = blockIdx.y * 128;
    int b  = blockIdx.z;
    const ushort* Abase = attnb + ((size_t)b * TT + m0) * CC;
    const ushort* Bbase = wob + (size_t)n0 * CC;
    f32x4 acc[4][4];
    for (int mt = 0; mt < 4; ++mt)
        for (int nt = 0; nt < 4; ++nt)
            acc[mt][nt] = (f32x4){0.f, 0.f, 0.f, 0.f};

    for (int k0 = 0; k0 < CC; k0 += 64) {
        __syncthreads();
#pragma unroll
        for (int it = 0; it < 4; ++it) {
            int i = w * 4 + it;
            int row = (i >> 1) * 16 + (lane & 15);
            int ch  = (i & 1) * 4 + (lane >> 4);
            ((uint4*)As)[i * 64 + lane] = *(const uint4*)(Abase + (size_t)row * CC + k0 + ch * 8);
            ((uint4*)Bs)[i * 64 + lane] = *(const uint4*)(Bbase + (size_t)row * CC + k0 + ch * 8);
        }
        __syncthreads();
#pragma unroll
        for (int ks = 0; ks < 2; ++ks) {
            bf16x8 af[4], bfr[4];
#pragma unroll
            for (int mt = 0; mt < 4; ++mt)
                af[mt] = *(const bf16x8*)&As[(((wm * 4 + mt) * 2 + ks) * 64 + lane) * 8];
#pragma unroll
            for (int nt = 0; nt < 4; ++nt)
                bfr[nt] = *(const bf16x8*)&Bs[(((wn * 4 + nt) * 2 + ks) * 64 + lane) * 8];
#pragma unroll
            for (int mt = 0; mt < 4; ++mt)
#pragma unroll
                for (int nt = 0; nt < 4; ++nt)
                    acc[mt][nt] = __builtin_amdgcn_mfma_f32_16x16x32_bf16(af[mt], bfr[nt], acc[mt][nt], 0, 0, 0);
        }
    }
    int c = lane & 15, g = lane >> 4;
    float bo[4];
    for (int nt = 0; nt < 4; ++nt) bo[nt] = bout[n0 + wn * 64 + nt * 16 + c];
#pragma unroll
    for (int mt = 0; mt < 4; ++mt)
        for (int r = 0; r < 4; ++r) {
            int t = m0 + wm * 64 + mt * 16 + g * 4 + r;
            float* hrow = hbuf + ((size_t)b * TT + t) * CC;
            const ushort* xr = xt + ((size_t)b * TT + t) * CC;
            for (int nt = 0; nt < 4; ++nt) {
                int i = n0 + wn * 64 + nt * 16 + c;
                hrow[i] = acc[mt][nt][r] + bo[nt] + bf2f(xr[i]);
            }
        }
}

// ---------------------------------------------------------------- LN stats (wave per row)
__global__ __launch_bounds__(256) void ln_stats_k(const float* __restrict__ hbuf,
                                                  float* __restrict__ mu,
                                                  float* __restrict__ rstd) {
    int tid = threadIdx.x;
    int lane = tid & 63, wid = tid >> 6;
    int row = blockIdx.x * 4 + wid;
    const float* hr = hbuf + (size_t)row * CC;
    float s = 0.f, sq = 0.f;
    for (int k = 0; k < CC / 64; ++k) {
        float v = hr[lane + 64 * k];
        s += v; sq += v * v;
    }
    for (int off = 32; off > 0; off >>= 1) {
        s  += __shfl_down(s, off);
        sq += __shfl_down(sq, off);
    }
    if (lane == 0) {
        float m = s / CC;
        float var = sq / CC - m * m;
        mu[row] = m;
        rstd[row] = rsqrtf(var + EPS);
    }
}

// ---------------------------------------------------------------- LN apply + transpose to (B,C,T)
__global__ __launch_bounds__(256) void ln_write_k(const float* __restrict__ hbuf,
                                                  const float* __restrict__ mu,
                                                  const float* __restrict__ rstd,
                                                  const float* __restrict__ gamma,
                                                  const float* __restrict__ beta,
                                                  float* __restrict__ out) {
    __shared__ float Ts[64][65];
    __shared__ float mus[64], rs[64];
    int tid = threadIdx.x;
    int t0 = blockIdx.x * 64, c0 = blockIdx.y * 64, b = blockIdx.z;
    if (tid < 64) {
        mus[tid] = mu[(size_t)b * TT + t0 + tid];
        rs[tid]  = rstd[(size_t)b * TT + t0 + tid];
    }
    __syncthreads();
    int cl = tid & 63, r0 = tid >> 6;
    float g = gamma[c0 + cl], be = beta[c0 + cl];
    for (int k = 0; k < 16; ++k) {
        int tl = r0 + 4 * k;
        float v = hbuf[((size_t)b * TT + t0 + tl) * CC + c0 + cl];
        Ts[tl][cl] = (v - mus[tl]) * rs[tl] * g + be;
    }
    __syncthreads();
    int tl2 = tid & 63;
    for (int k = 0; k < 16; ++k) {
        int c2 = r0 + 4 * k;
        out[((size_t)b * CC + c0 + c2) * TT + t0 + tl2] = Ts[tl2][c2];
    }
}

// ----------------------------------------------------------------
extern "C" void kernel_launch(void* const* d_in, const int* in_sizes, int n_in,
                              void* d_out, int out_size, void* d_ws, size_t ws_size,
                              hipStream_t stream) {
    const float* x      = (const float*)d_in[0];
    const float* sqi    = (const float*)d_in[1];
    const float* w_qkv  = (const float*)d_in[2];
    const float* w_out  = (const float*)d_in[3];
    const float* b_out  = (const float*)d_in[4];
    const float* w_conv = (const float*)d_in[5];
    const float* b_conv = (const float*)d_in[6];
    const float* gamma  = (const float*)d_in[7];
    const float* beta   = (const float*)d_in[8];
    float* out = (float*)d_out;

    ushort* qkvbuf = (ushort*)d_ws;                          // B*3*C*T bf16
    ushort* xt     = qkvbuf + (size_t)BB * 3 * CC * TT;      // B*T*C bf16
    ushort* attnb  = xt + (size_t)BB * TT * CC;              // B*T*C bf16
    ushort* wqb    = attnb + (size_t)BB * TT * CC;           // 3C*C bf16
    ushort* wob    = wqb + 3 * CC * CC;                      // C*C bf16
    float*  biasb  = (float*)(wob + CC * CC);                // B*T
    float*  mu     = biasb + BB * TT;
    float*  rstd   = mu + BB * TT;
    float*  hbuf   = (float*)d_ws;                           // reuse qkv region post-attention

    conv_bias_k<<<dim3((BB * TT) / 256), 256, 0, stream>>>(sqi, w_conv, b_conv, biasb);
    w_cast_k<<<dim3((4 * CC * CC) / 256), 256, 0, stream>>>(w_qkv, w_out, wqb, wob);
    xt_cast_k<<<dim3(TT / 64, CC / 64, BB), 256, 0, stream>>>(x, xt);
    qkv_mfma_k<<<dim3(TT / 128, (3 * CC) / 128, BB), 256, 0, stream>>>(xt, wqb, qkvbuf);
    attention_k<<<dim3(TT / 128, HH, BB), 256, 0, stream>>>(qkvbuf, biasb, attnb);
    out_proj_mfma_k<<<dim3(TT / 128, CC / 128, BB), 256, 0, stream>>>(attnb, wob, b_out, xt, hbuf);
    ln_stats_k<<<dim3((BB * TT) / 4), 256, 0, stream>>>(hbuf, mu, rstd);
    ln_write_k<<<dim3(TT / 64, CC / 64, BB), 256, 0, stream>>>(hbuf, mu, rstd, gamma, beta, out);
}

// Round 5
// 216.552 us; speedup vs baseline: 5.5726x; 1.0538x over previous
//
#include <hip/hip_runtime.h>
#include <math.h>

// Problem constants (LogitBiasedSelfAttention1D): B=4, C=512, T=2048, H=8, D=64
#define BB 4
#define CC 512
#define TT 2048
#define HH 8
#define DD 64
#define SCALE 0.125f
#define EPS 1e-5f

typedef __attribute__((ext_vector_type(8))) short bf16x8;   // 8 bf16 = 4 VGPRs (MFMA A/B frag)
typedef __attribute__((ext_vector_type(4))) float f32x4;    // MFMA C/D frag

__device__ inline ushort f2bf(float f) {           // RNE fp32 -> bf16
    unsigned int u = __builtin_bit_cast(unsigned int, f);
    u = (u + 0x7fff + ((u >> 16) & 1)) >> 16;
    return (ushort)u;
}
__device__ inline float bf2f(ushort u) {
    unsigned int v = ((unsigned int)u) << 16;
    return __builtin_bit_cast(float, v);
}
__device__ inline unsigned int pack2bf(float a, float b) {  // cheap near-RNE pack
    unsigned int ua = __builtin_bit_cast(unsigned int, a);
    unsigned int ub = __builtin_bit_cast(unsigned int, b);
    return ((ua + 0x8000u) >> 16) | ((ub + 0x8000u) & 0xffff0000u);
}

// ---------------------------------------------------------------- conv bias -> exp(bias)
__global__ void conv_ebias_k(const float* __restrict__ sqi,
                             const float* __restrict__ wc,
                             const float* __restrict__ bc,
                             float* __restrict__ ebias,
                             ushort* __restrict__ ebf) {
    int idx = blockIdx.x * 256 + threadIdx.x;
    if (idx >= BB * TT) return;
    int t = idx & (TT - 1);
    float l = (t > 0)      ? sqi[idx - 1] : 0.f;
    float m = sqi[idx];
    float r = (t < TT - 1) ? sqi[idx + 1] : 0.f;
    float eb = __expf(wc[0] * l + wc[1] * m + wc[2] * r + bc[0]);
    ebias[idx] = eb;
    ebf[idx] = f2bf(eb);
}

// ---------------------------------------------------------------- weight cast fp32->bf16
__global__ void w_cast_k(const float* __restrict__ wq, const float* __restrict__ wo,
                         ushort* __restrict__ wqb, ushort* __restrict__ wob) {
    int idx = blockIdx.x * 256 + threadIdx.x;
    if (idx < 3 * CC * CC) wqb[idx] = f2bf(wq[idx]);
    else                   wob[idx - 3 * CC * CC] = f2bf(wo[idx - 3 * CC * CC]);
}

// ---------------------------------------------------------------- x (b,c,t) fp32 -> xt (b,t,c) bf16
__global__ __launch_bounds__(256) void xt_cast_k(const float* __restrict__ x,
                                                 ushort* __restrict__ xt) {
    __shared__ float Ts[64][65];
    int tid = threadIdx.x;
    int t0 = blockIdx.x * 64, c0 = blockIdx.y * 64, b = blockIdx.z;
    int tl = tid & 63, r0 = tid >> 6;
    for (int k = 0; k < 16; ++k) {
        int cr = r0 * 16 + k;
        Ts[cr][tl] = x[((size_t)b * CC + c0 + cr) * TT + t0 + tl];
    }
    __syncthreads();
    int cl = tid & 63;
    for (int k = 0; k < 16; ++k) {
        int tw = r0 * 16 + k;
        xt[((size_t)b * TT + t0 + tw) * CC + c0 + cl] = f2bf(Ts[cl][tw]);
    }
}

// ---------------------------------------------------------------- QKV GEMM (bf16 MFMA)
// q -> (b,h,t,d) pre-scaled by SCALE; k -> (b,h,t,d); v -> (b,h,d,t) pre-scaled by exp(bias[t])
__global__ __launch_bounds__(256) void qkv_mfma_k(const ushort* __restrict__ xt,
                                                  const ushort* __restrict__ wqb,
                                                  const float* __restrict__ ebias,
                                                  ushort* __restrict__ qkv) {
    __shared__ ushort LDSb[17408];          // As[0..8192) Bs[8192..16384); epilogue 128x136
    ushort* As = LDSb;
    ushort* Bs = LDSb + 8192;
    int tid = threadIdx.x;
    int lane = tid & 63, w = tid >> 6;
    int wm = w & 1, wn = w >> 1;
    int m0 = blockIdx.x * 128;
    int j0 = blockIdx.y * 128;
    int b  = blockIdx.z;
    const ushort* Abase = xt + ((size_t)b * TT + m0) * CC;
    const ushort* Bbase = wqb + (size_t)j0 * CC;
    f32x4 acc[4][4];
    for (int mt = 0; mt < 4; ++mt)
        for (int nt = 0; nt < 4; ++nt)
            acc[mt][nt] = (f32x4){0.f, 0.f, 0.f, 0.f};

    for (int k0 = 0; k0 < CC; k0 += 64) {
        __syncthreads();
#pragma unroll
        for (int it = 0; it < 4; ++it) {
            int i = w * 4 + it;
            int row = (i >> 1) * 16 + (lane & 15);
            int ch  = (i & 1) * 4 + (lane >> 4);
            ((uint4*)As)[i * 64 + lane] = *(const uint4*)(Abase + (size_t)row * CC + k0 + ch * 8);
            ((uint4*)Bs)[i * 64 + lane] = *(const uint4*)(Bbase + (size_t)row * CC + k0 + ch * 8);
        }
        __syncthreads();
#pragma unroll
        for (int ks = 0; ks < 2; ++ks) {
            bf16x8 af[4], bfr[4];
#pragma unroll
            for (int mt = 0; mt < 4; ++mt)
                af[mt] = *(const bf16x8*)&As[(((wm * 4 + mt) * 2 + ks) * 64 + lane) * 8];
#pragma unroll
            for (int nt = 0; nt < 4; ++nt)
                bfr[nt] = *(const bf16x8*)&Bs[(((wn * 4 + nt) * 2 + ks) * 64 + lane) * 8];
#pragma unroll
            for (int mt = 0; mt < 4; ++mt)
#pragma unroll
                for (int nt = 0; nt < 4; ++nt)
                    acc[mt][nt] = __builtin_amdgcn_mfma_f32_16x16x32_bf16(af[mt], bfr[nt], acc[mt][nt], 0, 0, 0);
        }
    }
    int which = j0 >> 9;
    int c = lane & 15, g = lane >> 4;
    __syncthreads();
    if (which < 2) {
        float qs = (which == 0) ? SCALE : 1.0f;
#pragma unroll
        for (int mt = 0; mt < 4; ++mt)
            for (int r = 0; r < 4; ++r) {
                int row = wm * 64 + mt * 16 + g * 4 + r;
                for (int nt = 0; nt < 4; ++nt)
                    LDSb[row * 136 + wn * 64 + nt * 16 + c] = f2bf(acc[mt][nt][r] * qs);
            }
    } else {
#pragma unroll
        for (int mt = 0; mt < 4; ++mt)
            for (int r = 0; r < 4; ++r) {
                int row = wm * 64 + mt * 16 + g * 4 + r;
                float eb = ebias[(size_t)b * TT + m0 + row];      // V' = exp(bias[t]) * v
                for (int nt = 0; nt < 4; ++nt)
                    LDSb[(wn * 64 + nt * 16 + c) * 136 + row] = f2bf(acc[mt][nt][r] * eb);
            }
    }
    __syncthreads();
    if (which < 2) {
        ushort* base = qkv + (size_t)(b * 3 + which) * HH * TT * DD;
#pragma unroll
        for (int it = 0; it < 8; ++it) {
            int f = it * 256 + tid;
            int row = f >> 4, ch = f & 15;
            uint4 val = *(const uint4*)&LDSb[row * 136 + ch * 8];
            int jj = (j0 & 511) + ch * 8;
            int h = jj >> 6, d = jj & 63;
            *(uint4*)(base + ((size_t)h * TT + m0 + row) * DD + d) = val;
        }
    } else {
        ushort* base = qkv + (size_t)(b * 3 + 2) * HH * TT * DD;
#pragma unroll
        for (int it = 0; it < 8; ++it) {
            int f = it * 256 + tid;
            int drow = f >> 4, tch = f & 15;
            uint4 val = *(const uint4*)&LDSb[drow * 136 + tch * 8];
            int jj = (j0 & 511) + drow;
            int h = jj >> 6, d = jj & 63;
            *(uint4*)(base + ((size_t)h * DD + d) * TT + m0 + tch * 8) = val;
        }
    }
}

// ---------------------------------------------------------------- attention (bf16 MFMA)
// no max-subtraction: P = exp(q·k_scaled); denominator l = P·exp(bias) via MFMA;
// V pre-scaled by exp(bias) so out = (P·V')/l. block = 128 q rows x (h,b), 4 waves.
__global__ __launch_bounds__(256, 2) void attention_k(const ushort* __restrict__ qkv,
                                                      const ushort* __restrict__ ebf,
                                                      ushort* __restrict__ attnb) {
    __shared__ ushort QP[9216];     // Q stage (128x64), then P[128][72]
    __shared__ ushort Kf[4096];
    __shared__ ushort Vf[4096];
    __shared__ ushort ebs[64];
    int tid = threadIdx.x;
    int lane = tid & 63, w = tid >> 6;
    int c = lane & 15, g = lane >> 4;
    int q0 = blockIdx.x * 128, h = blockIdx.y, b = blockIdx.z;
    const ushort* qb = qkv + ((size_t)((b * 3 + 0) * HH + h)) * TT * DD;   // (t,d), pre-scaled
    const ushort* kb = qkv + ((size_t)((b * 3 + 1) * HH + h)) * TT * DD;   // (t,d)
    const ushort* vb = qkv + ((size_t)((b * 3 + 2) * HH + h)) * TT * DD;   // (d,t), eb-scaled

#pragma unroll
    for (int it = 0; it < 4; ++it) {
        int i = w * 4 + it;
        int row = (i >> 1) * 16 + c;
        int ch  = (i & 1) * 4 + g;
        ((uint4*)QP)[i * 64 + lane] = *(const uint4*)(qb + (size_t)(q0 + row) * DD + ch * 8);
    }
    __syncthreads();
    bf16x8 qfrag[2][2];
    for (int qg = 0; qg < 2; ++qg)
        for (int ks = 0; ks < 2; ++ks)
            qfrag[qg][ks] = *(const bf16x8*)&QP[(((qg * 4 + w) * 2 + ks) * 64 + lane) * 8];

    f32x4 oacc[2][4];
    f32x4 lacc[2];
    for (int qg = 0; qg < 2; ++qg) {
        lacc[qg] = (f32x4){0.f, 0.f, 0.f, 0.f};
        for (int dt = 0; dt < 4; ++dt) oacc[qg][dt] = (f32x4){0.f, 0.f, 0.f, 0.f};
    }

    for (int s0 = 0; s0 < TT; s0 += 64) {
        __syncthreads();
#pragma unroll
        for (int it = 0; it < 2; ++it) {
            int i = w * 2 + it;
            int row = (i >> 1) * 16 + c;
            int ch  = (i & 1) * 4 + g;
            ((uint4*)Kf)[i * 64 + lane] = *(const uint4*)(kb + (size_t)(s0 + row) * DD + ch * 8);
            ((uint4*)Vf)[i * 64 + lane] = *(const uint4*)(vb + (size_t)row * TT + s0 + ch * 8);
        }
        if (tid < 32) ((uint*)ebs)[tid] = *((const uint*)(ebf + (size_t)b * TT + s0) + tid);
        __syncthreads();

        bf16x8 kf[4][2];
#pragma unroll
        for (int mt = 0; mt < 4; ++mt)
            for (int ks = 0; ks < 2; ++ks)
                kf[mt][ks] = *(const bf16x8*)&Kf[((mt * 2 + ks) * 64 + lane) * 8];

#pragma unroll
        for (int qg = 0; qg < 2; ++qg) {
            f32x4 st[4];
#pragma unroll
            for (int mt = 0; mt < 4; ++mt) {
                f32x4 acc = (f32x4){0.f, 0.f, 0.f, 0.f};
                for (int ks = 0; ks < 2; ++ks)
                    acc = __builtin_amdgcn_mfma_f32_16x16x32_bf16(kf[mt][ks], qfrag[qg][ks], acc, 0, 0, 0);
                st[mt] = acc;
            }
            int qrow = (qg * 4 + w) * 16 + c;
#pragma unroll
            for (int mt = 0; mt < 4; ++mt) {
                uint2 pk;
                pk.x = pack2bf(__expf(st[mt][0]), __expf(st[mt][1]));
                pk.y = pack2bf(__expf(st[mt][2]), __expf(st[mt][3]));
                *(uint2*)&QP[qrow * 72 + mt * 16 + g * 4] = pk;
            }
        }

        bf16x8 vf[4][2], ebfrag[2];
#pragma unroll
        for (int dt = 0; dt < 4; ++dt)
            for (int ks = 0; ks < 2; ++ks)
                vf[dt][ks] = *(const bf16x8*)&Vf[((dt * 2 + ks) * 64 + lane) * 8];
        for (int ks = 0; ks < 2; ++ks)
            ebfrag[ks] = *(const bf16x8*)&ebs[ks * 32 + g * 8];   // broadcast across c

#pragma unroll
        for (int qg = 0; qg < 2; ++qg) {
            int qrow = (qg * 4 + w) * 16 + c;
            bf16x8 pb[2];
            for (int ks = 0; ks < 2; ++ks)
                pb[ks] = *(const bf16x8*)&QP[qrow * 72 + ks * 32 + g * 8];
#pragma unroll
            for (int dt = 0; dt < 4; ++dt) {
                f32x4 acc = oacc[qg][dt];
                for (int ks = 0; ks < 2; ++ks)
                    acc = __builtin_amdgcn_mfma_f32_16x16x32_bf16(vf[dt][ks], pb[ks], acc, 0, 0, 0);
                oacc[qg][dt] = acc;
            }
            for (int ks = 0; ks < 2; ++ks)
                lacc[qg] = __builtin_amdgcn_mfma_f32_16x16x32_bf16(ebfrag[ks], pb[ks], lacc[qg], 0, 0, 0);
        }
    }
#pragma unroll
    for (int qg = 0; qg < 2; ++qg) {
        float inv = 1.f / lacc[qg][0];
        int t = q0 + (qg * 4 + w) * 16 + c;
        ushort* ob = attnb + ((size_t)b * TT + t) * CC + h * DD;
        for (int dt = 0; dt < 4; ++dt) {
            ushort4 pk;
            pk.x = f2bf(oacc[qg][dt][0] * inv); pk.y = f2bf(oacc[qg][dt][1] * inv);
            pk.z = f2bf(oacc[qg][dt][2] * inv); pk.w = f2bf(oacc[qg][dt][3] * inv);
            *(ushort4*)(ob + dt * 16 + g * 4) = pk;
        }
    }
}

// ---------------------------------------------------------------- out proj (bf16 MFMA) + bias + residual
__global__ __launch_bounds__(256) void out_proj_mfma_k(const ushort* __restrict__ attnb,
                                                       const ushort* __restrict__ wob,
                                                       const float* __restrict__ bout,
                                                       const ushort* __restrict__ xt,
                                                       float* __restrict__ hbuf) {
    __shared__ ushort As[8192];
    __shared__ ushort Bs[8192];
    int tid = threadIdx.x;
    int lane = tid & 63, w = tid >> 6;
    int wm = w & 1, wn = w >> 1;
    int m0 = blockIdx.x * 128;
    int n0 = blockIdx.y * 128;
    int b  = blockIdx.z;
    const ushort* Abase = attnb + ((size_t)b * TT + m0) * CC;
    const ushort* Bbase = wob + (size_t)n0 * CC;
    f32x4 acc[4][4];
    for (int mt = 0; mt < 4; ++mt)
        for (int nt = 0; nt < 4; ++nt)
            acc[mt][nt] = (f32x4){0.f, 0.f, 0.f, 0.f};

    for (int k0 = 0; k0 < CC; k0 += 64) {
        __syncthreads();
#pragma unroll
        for (int it = 0; it < 4; ++it) {
            int i = w * 4 + it;
            int row = (i >> 1) * 16 + (lane & 15);
            int ch  = (i & 1) * 4 + (lane >> 4);
            ((uint4*)As)[i * 64 + lane] = *(const uint4*)(Abase + (size_t)row * CC + k0 + ch * 8);
            ((uint4*)Bs)[i * 64 + lane] = *(const uint4*)(Bbase + (size_t)row * CC + k0 + ch * 8);
        }
        __syncthreads();
#pragma unroll
        for (int ks = 0; ks < 2; ++ks) {
            bf16x8 af[4], bfr[4];
#pragma unroll
            for (int mt = 0; mt < 4; ++mt)
                af[mt] = *(const bf16x8*)&As[(((wm * 4 + mt) * 2 + ks) * 64 + lane) * 8];
#pragma unroll
            for (int nt = 0; nt < 4; ++nt)
                bfr[nt] = *(const bf16x8*)&Bs[(((wn * 4 + nt) * 2 + ks) * 64 + lane) * 8];
#pragma unroll
            for (int mt = 0; mt < 4; ++mt)
#pragma unroll
                for (int nt = 0; nt < 4; ++nt)
                    acc[mt][nt] = __builtin_amdgcn_mfma_f32_16x16x32_bf16(af[mt], bfr[nt], acc[mt][nt], 0, 0, 0);
        }
    }
    int c = lane & 15, g = lane >> 4;
    float bo[4];
    for (int nt = 0; nt < 4; ++nt) bo[nt] = bout[n0 + wn * 64 + nt * 16 + c];
#pragma unroll
    for (int mt = 0; mt < 4; ++mt)
        for (int r = 0; r < 4; ++r) {
            int t = m0 + wm * 64 + mt * 16 + g * 4 + r;
            float* hrow = hbuf + ((size_t)b * TT + t) * CC;
            const ushort* xr = xt + ((size_t)b * TT + t) * CC;
            for (int nt = 0; nt < 4; ++nt) {
                int i = n0 + wn * 64 + nt * 16 + c;
                hrow[i] = acc[mt][nt][r] + bo[nt] + bf2f(xr[i]);
            }
        }
}

// ---------------------------------------------------------------- LN stats (wave per row)
__global__ __launch_bounds__(256) void ln_stats_k(const float* __restrict__ hbuf,
                                                  float* __restrict__ mu,
                                                  float* __restrict__ rstd) {
    int tid = threadIdx.x;
    int lane = tid & 63, wid = tid >> 6;
    int row = blockIdx.x * 4 + wid;
    const float* hr = hbuf + (size_t)row * CC;
    float s = 0.f, sq = 0.f;
    for (int k = 0; k < CC / 64; ++k) {
        float v = hr[lane + 64 * k];
        s += v; sq += v * v;
    }
    for (int off = 32; off > 0; off >>= 1) {
        s  += __shfl_down(s, off);
        sq += __shfl_down(sq, off);
    }
    if (lane == 0) {
        float m = s / CC;
        float var = sq / CC - m * m;
        mu[row] = m;
        rstd[row] = rsqrtf(var + EPS);
    }
}

// ---------------------------------------------------------------- LN apply + transpose to (B,C,T)
__global__ __launch_bounds__(256) void ln_write_k(const float* __restrict__ hbuf,
                                                  const float* __restrict__ mu,
                                                  const float* __restrict__ rstd,
                                                  const float* __restrict__ gamma,
                                                  const float* __restrict__ beta,
                                                  float* __restrict__ out) {
    __shared__ float Ts[64][65];
    __shared__ float mus[64], rs[64];
    int tid = threadIdx.x;
    int t0 = blockIdx.x * 64, c0 = blockIdx.y * 64, b = blockIdx.z;
    if (tid < 64) {
        mus[tid] = mu[(size_t)b * TT + t0 + tid];
        rs[tid]  = rstd[(size_t)b * TT + t0 + tid];
    }
    __syncthreads();
    int cl = tid & 63, r0 = tid >> 6;
    float g = gamma[c0 + cl], be = beta[c0 + cl];
    for (int k = 0; k < 16; ++k) {
        int tl = r0 + 4 * k;
        float v = hbuf[((size_t)b * TT + t0 + tl) * CC + c0 + cl];
        Ts[tl][cl] = (v - mus[tl]) * rs[tl] * g + be;
    }
    __syncthreads();
    int tl2 = tid & 63;
    for (int k = 0; k < 16; ++k) {
        int c2 = r0 + 4 * k;
        out[((size_t)b * CC + c0 + c2) * TT + t0 + tl2] = Ts[tl2][c2];
    }
}

// ----------------------------------------------------------------
extern "C" void kernel_launch(void* const* d_in, const int* in_sizes, int n_in,
                              void* d_out, int out_size, void* d_ws, size_t ws_size,
                              hipStream_t stream) {
    const float* x      = (const float*)d_in[0];
    const float* sqi    = (const float*)d_in[1];
    const float* w_qkv  = (const float*)d_in[2];
    const float* w_out  = (const float*)d_in[3];
    const float* b_out  = (const float*)d_in[4];
    const float* w_conv = (const float*)d_in[5];
    const float* b_conv = (const float*)d_in[6];
    const float* gamma  = (const float*)d_in[7];
    const float* beta   = (const float*)d_in[8];
    float* out = (float*)d_out;

    ushort* qkvbuf = (ushort*)d_ws;                          // B*3*C*T bf16
    ushort* xt     = qkvbuf + (size_t)BB * 3 * CC * TT;      // B*T*C bf16
    ushort* attnb  = xt + (size_t)BB * TT * CC;              // B*T*C bf16
    ushort* wqb    = attnb + (size_t)BB * TT * CC;           // 3C*C bf16
    ushort* wob    = wqb + 3 * CC * CC;                      // C*C bf16
    ushort* ebf    = wob + CC * CC;                          // B*T bf16
    float*  ebias  = (float*)(ebf + BB * TT);                // B*T fp32
    float*  mu     = ebias + BB * TT;
    float*  rstd   = mu + BB * TT;
    float*  hbuf   = (float*)d_ws;                           // reuse qkv region post-attention

    conv_ebias_k<<<dim3((BB * TT) / 256), 256, 0, stream>>>(sqi, w_conv, b_conv, ebias, ebf);
    w_cast_k<<<dim3((4 * CC * CC) / 256), 256, 0, stream>>>(w_qkv, w_out, wqb, wob);
    xt_cast_k<<<dim3(TT / 64, CC / 64, BB), 256, 0, stream>>>(x, xt);
    qkv_mfma_k<<<dim3(TT / 128, (3 * CC) / 128, BB), 256, 0, stream>>>(xt, wqb, ebias, qkvbuf);
    attention_k<<<dim3(TT / 128, HH, BB), 256, 0, stream>>>(qkvbuf, ebf, attnb);
    out_proj_mfma_k<<<dim3(TT / 128, CC / 128, BB), 256, 0, stream>>>(attnb, wob, b_out, xt, hbuf);
    ln_stats_k<<<dim3((BB * TT) / 4), 256, 0, stream>>>(hbuf, mu, rstd);
    ln_write_k<<<dim3(TT / 64, CC / 64, BB), 256, 0, stream>>>(hbuf, mu, rstd, gamma, beta, out);
}